// Round 3
// baseline (7072.648 us; speedup 1.0000x reference)
//
#include <hip/hip_runtime.h>
#include <cmath>

// ---------------- problem constants ----------------
constexpr int BATCH = 4096;
constexpr int NG    = 8;
constexpr float EPSN = 1e-4f;

// d_out layout (floats): [new_stoch | new_deter | logit]
constexpr int OFF_STOCH = 0;
constexpr int OFF_DETER = BATCH * 512;
constexpr int OFF_LOGIT = OFF_DETER + BATCH * 2048;

// ws layout (floats)
constexpr size_t WS_WTH = 0;                                // 8*1024*256
constexpr size_t WS_WTG = WS_WTH + (size_t)NG * 1024 * 256; // 8*256*768
constexpr size_t WS_X   = WS_WTG + (size_t)NG * 256 * 768;  // 4096*768
constexpr size_t WS_XH  = WS_X + (size_t)BATCH * 768;       // 4096*2048 (also 8x splitK partials)
constexpr size_t WS_H   = WS_XH + (size_t)BATCH * 2048;     // 4096*256

#define DINLINE __device__ __forceinline__

DINLINE float sigm(float x)  { return 1.0f / (1.0f + expf(-x)); }
DINLINE float siluf(float x) { return x / (1.0f + expf(-x)); }

DINLINE float4 ld4(const float* p) { return *reinterpret_cast<const float4*>(p); }
DINLINE void st4(float* p, float4 v) { *reinterpret_cast<float4*>(p) = v; }

// rmsnorm(256)+silu epilogue: lane holds 4 values of one row, full wave = 256 cols.
DINLINE float4 rms_silu4(float v0, float v1, float v2, float v3, float4 s4) {
  float ss = v0 * v0 + v1 * v1 + v2 * v2 + v3 * v3;
#pragma unroll
  for (int off = 32; off; off >>= 1) ss += __shfl_xor(ss, off);
  float inv = 1.0f / sqrtf(ss * (1.0f / 256.0f) + EPSN);
  float4 o;
  o.x = siluf(v0 * inv * s4.x); o.y = siluf(v1 * inv * s4.y);
  o.z = siluf(v2 * inv * s4.z); o.w = siluf(v3 * inv * s4.w);
  return o;
}

// ---------------- compute core ----------------
// 512 threads, 8 waves. Wave wv owns rows [wv*TM,(wv+1)*TM). Lane owns cols s*256+tx*4.
template<int TM, int TN4, int KC>
DINLINE void mm_chunk(const float* __restrict__ A_s, const float* __restrict__ W_s,
                      float (&acc)[TM][TN4][4], int tx, int wv) {
  constexpr int BN = 256 * TN4;
#pragma unroll
  for (int kk4 = 0; kk4 < KC / 4; ++kk4) {
    float4 w[4][TN4];
#pragma unroll
    for (int j = 0; j < 4; ++j)
#pragma unroll
      for (int s = 0; s < TN4; ++s)
        w[j][s] = ld4(W_s + (kk4 * 4 + j) * BN + s * 256 + tx * 4);
#pragma unroll
    for (int i = 0; i < TM; ++i) {
      float4 a = ld4(A_s + (wv * TM + i) * KC + kk4 * 4);
#pragma unroll
      for (int j = 0; j < 4; ++j) {
        float av = (&a.x)[j];
#pragma unroll
        for (int s = 0; s < TN4; ++s) {
          acc[i][s][0] = fmaf(av, w[j][s].x, acc[i][s][0]);
          acc[i][s][1] = fmaf(av, w[j][s].y, acc[i][s][1]);
          acc[i][s][2] = fmaf(av, w[j][s].z, acc[i][s][2]);
          acc[i][s][3] = fmaf(av, w[j][s].w, acc[i][s][3]);
        }
      }
    }
  }
}

// ---------------- kernel 1: tiled weight transpose ----------------
__global__ __launch_bounds__(256) void k_transpose2(
    const float* __restrict__ hk, const float* __restrict__ gk,
    float* __restrict__ wTh, float* __restrict__ wTg) {
  __shared__ float L[16 * 520];
  const int b = blockIdx.x, t = threadIdx.x;
  const float* src; float* dst; int I, O, o0, i0;
  if (b < 256) { src = hk; dst = wTh; I = 1024; O = 256;
                 int ot = b & 15, it = b >> 4; o0 = ot * 16; i0 = it * 64; }
  else         { src = gk; dst = wTg; I = 256;  O = 768;
                 int b2 = b - 256; int ot = b2 % 48, it = b2 / 48; o0 = ot * 16; i0 = it * 64; }
#pragma unroll
  for (int q = 0; q < 8; ++q) {
    int idx = q * 256 + t;
    int o_l = idx >> 7, rem = idx & 127, i_l = rem >> 1, gh = rem & 1;
    float4 v = ld4(src + ((size_t)(o0 + o_l) * I + i0 + i_l) * 8 + gh * 4);
    st4(&L[o_l * 520 + i_l * 8 + gh * 4], v);
  }
  __syncthreads();
#pragma unroll
  for (int q = 0; q < 8; ++q) {
    int idx = q * 256 + t;
    int g = idx >> 8, rem = idx & 255, i_l = rem >> 2, o4 = rem & 3;
    float4 v;
    v.x = L[(o4 * 4 + 0) * 520 + i_l * 8 + g];
    v.y = L[(o4 * 4 + 1) * 520 + i_l * 8 + g];
    v.z = L[(o4 * 4 + 2) * 520 + i_l * 8 + g];
    v.w = L[(o4 * 4 + 3) * 520 + i_l * 8 + g];
    st4(dst + ((size_t)g * I + i0 + i_l) * O + o0 + o4 * 4, v);
  }
}

// ---------------- pipelined TN4=1 GEMM macro-body ----------------
// BM=64, TM=8, KC=16, BN=256. LDS S[2][64*16 + 16*256]. Caller supplies A-load expr.
#define PIPE_DEFS \
  constexpr int TM = 8, KC = 16, BN = 256; \
  constexpr int AF = 64 * KC, WF = KC * BN; \
  __shared__ float S[2][AF + WF]; \
  const int tid = threadIdx.x, tx = tid & 63, wv = tid >> 6; \
  const int arow = tid >> 2, ac4 = (tid & 3) * 4; \
  float4 wreg0, wreg1, areg; \
  float acc[TM][1][4] = {}; \
  int cur = 0;

#define PIPE_LOADW(Wp, kk) \
  { const float* wp_ = (Wp) + (size_t)(kk) * BN; \
    wreg0 = ld4(wp_ + tid * 4); wreg1 = ld4(wp_ + 2048 + tid * 4); }

#define PIPE_WRITE(buf) \
  { st4(&S[buf][AF + tid * 4], wreg0); st4(&S[buf][AF + 2048 + tid * 4], wreg1); \
    if (tid < 256) st4(&S[buf][arow * KC + ac4], areg); }

// ---------------- kernel 2: input projections (x0 splitK8 | x1 | x2) ----------------
__global__ __launch_bounds__(512, 4) void k_inproj(
    const float* __restrict__ deter, const float* __restrict__ stoch,
    const float* __restrict__ action,
    const float* __restrict__ w0,
    const float* __restrict__ w1, const float* __restrict__ b1, const float* __restrict__ s1,
    const float* __restrict__ w2, const float* __restrict__ b2, const float* __restrict__ s2,
    float* __restrict__ part, float* __restrict__ xb) {
  const int bid = blockIdx.x;
  if (bid >= 576) {  // ---- x2: action (K=17), BM=128 ----
    constexpr int AF2 = 64 * 16 + 16 * 256;
    __shared__ float S2[2][AF2];
    float* W2s = &S2[0][0];          // 17*256 = 4352 <= AF2
    float* A2s = &S2[1][0];          // 128*20 = 2560 <= AF2
    const int tid = threadIdx.x, tx = tid & 63, wv = tid >> 6;
    const int m0 = (bid - 576) * 128;
    for (int e = tid; e < 17 * 256; e += 512) W2s[e] = w2[e];
    for (int e = tid; e < 128 * 17; e += 512) {
      int r = e / 17, c = e % 17;
      float a = action[(size_t)(m0 + r) * 17 + c];
      float m = fabsf(a);
      A2s[r * 20 + c] = a / (m > 1.f ? m : 1.f);
    }
    __syncthreads();
    float4 acc2[16];
#pragma unroll
    for (int r = 0; r < 16; ++r) acc2[r] = make_float4(0.f, 0.f, 0.f, 0.f);
#pragma unroll
    for (int k = 0; k < 17; ++k) {
      float4 w4 = ld4(W2s + k * 256 + tx * 4);
#pragma unroll
      for (int r = 0; r < 16; ++r) {
        float av = A2s[(wv * 16 + r) * 20 + k];
        acc2[r].x = fmaf(av, w4.x, acc2[r].x);
        acc2[r].y = fmaf(av, w4.y, acc2[r].y);
        acc2[r].z = fmaf(av, w4.z, acc2[r].z);
        acc2[r].w = fmaf(av, w4.w, acc2[r].w);
      }
    }
    float4 b4 = ld4(b2 + tx * 4);
    float4 s4 = ld4(s2 + tx * 4);
#pragma unroll
    for (int r = 0; r < 16; ++r) {
      float4 o = rms_silu4(acc2[r].x + b4.x, acc2[r].y + b4.y,
                           acc2[r].z + b4.z, acc2[r].w + b4.w, s4);
      st4(xb + (size_t)(m0 + wv * 16 + r) * 768 + 512 + tx * 4, o);
    }
    return;
  }

  PIPE_DEFS;
  if (bid < 512) {  // ---- x0: deter @ in0_w, split-K 8 ----
    const int ks = bid & 7, m0 = (bid >> 3) * 64, kbase = ks * 256;
    const float* W = w0 + (size_t)kbase * 256;
    const float* As = deter;
    PIPE_LOADW(W, 0);
    areg = ld4(As + (size_t)(m0 + arow) * 2048 + kbase + ac4);
    PIPE_WRITE(0);
    __syncthreads();
    for (int t = 0; t < 16; ++t) {
      if (t + 1 < 16) {
        PIPE_LOADW(W, (t + 1) * KC);
        areg = ld4(As + (size_t)(m0 + arow) * 2048 + kbase + (t + 1) * KC + ac4);
      }
      mm_chunk<TM, 1, KC>(&S[cur][0], &S[cur][AF], acc, tx, wv);
      if (t + 1 < 16) PIPE_WRITE(cur ^ 1);
      __syncthreads();
      cur ^= 1;
    }
#pragma unroll
    for (int i = 0; i < TM; ++i)
      st4(part + ((size_t)ks * BATCH + m0 + wv * TM + i) * 256 + tx * 4,
          make_float4(acc[i][0][0], acc[i][0][1], acc[i][0][2], acc[i][0][3]));
    return;
  }
  // ---- x1: stoch (K=512) ----
  {
    const int m0 = (bid - 512) * 64;
    PIPE_LOADW(w1, 0);
    areg = ld4(stoch + (size_t)(m0 + arow) * 512 + ac4);
    PIPE_WRITE(0);
    __syncthreads();
    for (int t = 0; t < 32; ++t) {
      if (t + 1 < 32) {
        PIPE_LOADW(w1, (t + 1) * KC);
        areg = ld4(stoch + (size_t)(m0 + arow) * 512 + (t + 1) * KC + ac4);
      }
      mm_chunk<TM, 1, KC>(&S[cur][0], &S[cur][AF], acc, tx, wv);
      if (t + 1 < 32) PIPE_WRITE(cur ^ 1);
      __syncthreads();
      cur ^= 1;
    }
    float4 b4 = ld4(b1 + tx * 4);
    float4 s4 = ld4(s1 + tx * 4);
#pragma unroll
    for (int i = 0; i < TM; ++i) {
      float4 o = rms_silu4(acc[i][0][0] + b4.x, acc[i][0][1] + b4.y,
                           acc[i][0][2] + b4.z, acc[i][0][3] + b4.w, s4);
      st4(xb + (size_t)(m0 + wv * TM + i) * 768 + 256 + tx * 4, o);
    }
  }
}

// ---------------- kernel 3: splitK-8 combine + bias + rmsnorm(256) + silu ----------------
__global__ __launch_bounds__(256) void k_combine8(
    const float* __restrict__ part, const float* __restrict__ bias,
    const float* __restrict__ scale, float* __restrict__ dst, int dstride) {
  const int tid = threadIdx.x, tx = tid & 63, wv = tid >> 6;
  const size_t row = blockIdx.x * 4 + wv;
  float4 v = make_float4(0.f, 0.f, 0.f, 0.f);
#pragma unroll
  for (int p = 0; p < 8; ++p) {
    float4 t = ld4(part + ((size_t)p * BATCH + row) * 256 + tx * 4);
    v.x += t.x; v.y += t.y; v.z += t.z; v.w += t.w;
  }
  float4 b4 = ld4(bias + tx * 4);
  float4 s4 = ld4(scale + tx * 4);
  float4 o = rms_silu4(v.x + b4.x, v.y + b4.y, v.z + b4.z, v.w + b4.w, s4);
  st4(dst + row * dstride + tx * 4, o);
}

// ---------------- kernel 4: hid0 block-linear (+bias) -> xh ----------------
__global__ __launch_bounds__(512, 4) void k_hid0(
    const float* __restrict__ deter, const float* __restrict__ xb,
    const float* __restrict__ wTh, const float* __restrict__ hbias,
    float* __restrict__ yh) {
  PIPE_DEFS;
  const int g = blockIdx.x & 7, m0 = (blockIdx.x >> 3) * 64;
  const float* W = wTh + (size_t)g * 1024 * 256;
  PIPE_LOADW(W, 0);
  areg = ld4(deter + (size_t)(m0 + arow) * 2048 + g * 256 + ac4);
  PIPE_WRITE(0);
  __syncthreads();
  for (int t = 0; t < 64; ++t) {
    if (t + 1 < 64) {
      int k = (t + 1) * KC + ac4;
      PIPE_LOADW(W, (t + 1) * KC);
      areg = (k < 256) ? ld4(deter + (size_t)(m0 + arow) * 2048 + g * 256 + k)
                       : ld4(xb + (size_t)(m0 + arow) * 768 + (k - 256));
    }
    mm_chunk<TM, 1, KC>(&S[cur][0], &S[cur][AF], acc, tx, wv);
    if (t + 1 < 64) PIPE_WRITE(cur ^ 1);
    __syncthreads();
    cur ^= 1;
  }
  float4 b4 = ld4(hbias + g * 256 + tx * 4);
#pragma unroll
  for (int i = 0; i < TM; ++i)
    st4(yh + (size_t)(m0 + wv * TM + i) * 2048 + g * 256 + tx * 4,
        make_float4(acc[i][0][0] + b4.x, acc[i][0][1] + b4.y,
                    acc[i][0][2] + b4.z, acc[i][0][3] + b4.w));
}

// ---------------- kernel 5: in-place rmsnorm(2048)+silu ----------------
__global__ __launch_bounds__(256) void k_rmsnorm2048(
    float* __restrict__ xh, const float* __restrict__ scale) {
  const int b = blockIdx.x, tid = threadIdx.x;
  float* row = xh + (size_t)b * 2048;
  float4 v0 = ld4(row + tid * 8);
  float4 v1 = ld4(row + tid * 8 + 4);
  float ss = v0.x * v0.x + v0.y * v0.y + v0.z * v0.z + v0.w * v0.w +
             v1.x * v1.x + v1.y * v1.y + v1.z * v1.z + v1.w * v1.w;
#pragma unroll
  for (int off = 32; off; off >>= 1) ss += __shfl_xor(ss, off);
  __shared__ float wsum[4];
  if ((tid & 63) == 0) wsum[tid >> 6] = ss;
  __syncthreads();
  float tot = wsum[0] + wsum[1] + wsum[2] + wsum[3];
  float inv = 1.0f / sqrtf(tot * (1.0f / 2048.0f) + EPSN);
  float4 sc0 = ld4(scale + tid * 8);
  float4 sc1 = ld4(scale + tid * 8 + 4);
  float4 o0, o1;
  o0.x = siluf(v0.x * inv * sc0.x); o0.y = siluf(v0.y * inv * sc0.y);
  o0.z = siluf(v0.z * inv * sc0.z); o0.w = siluf(v0.w * inv * sc0.w);
  o1.x = siluf(v1.x * inv * sc1.x); o1.y = siluf(v1.y * inv * sc1.y);
  o1.z = siluf(v1.z * inv * sc1.z); o1.w = siluf(v1.w * inv * sc1.w);
  st4(row + tid * 8, o0);
  st4(row + tid * 8 + 4, o1);
}

// ---------------- kernel 6: gru block-linear + fused GRU -> new_deter ----------------
// BN=768, TN4=3, BM=64, TM=8, KC=16; LDS 2*(1024+12288)*4 = 106.5 KB, 1 block/CU
__global__ __launch_bounds__(512, 2) void k_gru(
    const float* __restrict__ xh, const float* __restrict__ wTg,
    const float* __restrict__ gb, const float* __restrict__ deter,
    float* __restrict__ newdet) {
  constexpr int TM = 8, KC = 16, BN = 768;
  constexpr int AF = 64 * KC, WF = KC * BN;
  __shared__ float S[2][AF + WF];
  const int tid = threadIdx.x, tx = tid & 63, wv = tid >> 6;
  const int arow = tid >> 2, ac4 = (tid & 3) * 4;
  const int g = blockIdx.x & 7, m0 = (blockIdx.x >> 3) * 64;
  const float* W = wTg + (size_t)g * 256 * 768;
  float4 wr[6]; float4 areg;
  float acc[TM][3][4] = {};
  int cur = 0;
#pragma unroll
  for (int q = 0; q < 6; ++q) wr[q] = ld4(W + (q * 512 + tid) * 4);
  areg = ld4(xh + (size_t)(m0 + arow) * 2048 + g * 256 + ac4);
#pragma unroll
  for (int q = 0; q < 6; ++q) st4(&S[0][AF + (q * 512 + tid) * 4], wr[q]);
  if (tid < 256) st4(&S[0][arow * KC + ac4], areg);
  __syncthreads();
  for (int t = 0; t < 16; ++t) {
    if (t + 1 < 16) {
      const float* wp = W + (size_t)(t + 1) * KC * BN;
#pragma unroll
      for (int q = 0; q < 6; ++q) wr[q] = ld4(wp + (q * 512 + tid) * 4);
      areg = ld4(xh + (size_t)(m0 + arow) * 2048 + g * 256 + (t + 1) * KC + ac4);
    }
    mm_chunk<TM, 3, KC>(&S[cur][0], &S[cur][AF], acc, tx, wv);
    if (t + 1 < 16) {
#pragma unroll
      for (int q = 0; q < 6; ++q) st4(&S[cur ^ 1][AF + (q * 512 + tid) * 4], wr[q]);
      if (tid < 256) st4(&S[cur ^ 1][arow * KC + ac4], areg);
    }
    __syncthreads();
    cur ^= 1;
  }
  const int j0 = tx * 4;
  float4 br = ld4(gb + g * 768 + j0);
  float4 bc = ld4(gb + g * 768 + 256 + j0);
  float4 bu = ld4(gb + g * 768 + 512 + j0);
#pragma unroll
  for (int i = 0; i < TM; ++i) {
    size_t b = m0 + wv * TM + i;
    float4 d = ld4(deter + b * 2048 + g * 256 + j0);
    float4 o;
#pragma unroll
    for (int j = 0; j < 4; ++j) {
      float r = sigm(acc[i][0][j] + (&br.x)[j]);
      float c = acc[i][1][j] + (&bc.x)[j];
      float u = sigm(acc[i][2][j] + (&bu.x)[j] - 1.0f);
      (&o.x)[j] = u * tanhf(r * c) + (1.0f - u) * (&d.x)[j];
    }
    st4(newdet + b * 2048 + g * 256 + j0, o);
  }
}

// ---------------- kernel 7: obs_fc0 splitK-8 partials ----------------
__global__ __launch_bounds__(512, 4) void k_obsfc0(
    const float* __restrict__ newdet, const float* __restrict__ embed,
    const float* __restrict__ W0, float* __restrict__ part) {
  PIPE_DEFS;
  const int ks = blockIdx.x & 7, m0 = (blockIdx.x >> 3) * 64;
  const int kbase = ks * 384;
  const float* W = W0 + (size_t)kbase * 256;
  auto lda = [&](int k) -> float4 {
    int kk = kbase + k + ac4;
    return (kk < 2048) ? ld4(newdet + (size_t)(m0 + arow) * 2048 + kk)
                       : ld4(embed + (size_t)(m0 + arow) * 1024 + (kk - 2048));
  };
  PIPE_LOADW(W, 0);
  areg = lda(0);
  PIPE_WRITE(0);
  __syncthreads();
  for (int t = 0; t < 24; ++t) {
    if (t + 1 < 24) {
      PIPE_LOADW(W, (t + 1) * KC);
      areg = lda((t + 1) * KC);
    }
    mm_chunk<TM, 1, KC>(&S[cur][0], &S[cur][AF], acc, tx, wv);
    if (t + 1 < 24) PIPE_WRITE(cur ^ 1);
    __syncthreads();
    cur ^= 1;
  }
#pragma unroll
  for (int i = 0; i < TM; ++i)
    st4(part + ((size_t)ks * BATCH + m0 + wv * TM + i) * 256 + tx * 4,
        make_float4(acc[i][0][0], acc[i][0][1], acc[i][0][2], acc[i][0][3]));
}

// ---------------- kernel 8: obs_out -> logit + argmax one-hot ----------------
__global__ __launch_bounds__(512) void k_obs_out(
    const float* __restrict__ h, const float* __restrict__ W0,
    const float* __restrict__ ob, float* __restrict__ logit,
    float* __restrict__ stoch_out) {
  constexpr int TM = 4, KC = 16, BN = 512;
  __shared__ float A_s[32 * KC];
  __shared__ float W_s[KC * BN];
  const int tid = threadIdx.x, tx = tid & 63, wv = tid >> 6;
  const int m0 = blockIdx.x * 32;
  float acc[TM][2][4] = {};
  for (int k0 = 0; k0 < 256; k0 += KC) {
    { int r = tid >> 4, c = tid & 15;
      A_s[r * KC + c] = h[(size_t)(m0 + r) * 256 + k0 + c]; }
#pragma unroll
    for (int q = 0; q < 4; ++q) {
      int e4 = q * 512 + tid;
      st4(W_s + e4 * 4, ld4(W0 + (size_t)k0 * BN + e4 * 4));
    }
    __syncthreads();
    mm_chunk<TM, 2, KC>(A_s, W_s, acc, tx, wv);
    __syncthreads();
  }
  float4 b0 = ld4(ob + tx * 4);
  float4 b1 = ld4(ob + 256 + tx * 4);
#pragma unroll
  for (int i = 0; i < TM; ++i) {
    size_t b = m0 + wv * TM + i;
#pragma unroll
    for (int s = 0; s < 2; ++s) {
      float4 bb = s ? b1 : b0;
      float l0 = acc[i][s][0] + bb.x, l1 = acc[i][s][1] + bb.y;
      float l2 = acc[i][s][2] + bb.z, l3 = acc[i][s][3] + bb.w;
      int base = s * 256 + tx * 4;
      st4(logit + b * 512 + base, make_float4(l0, l1, l2, l3));
      float bv = l0; int bi = base;
      if (l1 > bv) { bv = l1; bi = base + 1; }
      if (l2 > bv) { bv = l2; bi = base + 2; }
      if (l3 > bv) { bv = l3; bi = base + 3; }
#pragma unroll
      for (int off = 1; off <= 2; off <<= 1) {
        float pv = __shfl_xor(bv, off);
        int   pi = __shfl_xor(bi, off);
        if (pv > bv || (pv == bv && pi < bi)) { bv = pv; bi = pi; }
      }
      float4 oh;
      oh.x = (base + 0 == bi) ? 1.f : 0.f;
      oh.y = (base + 1 == bi) ? 1.f : 0.f;
      oh.z = (base + 2 == bi) ? 1.f : 0.f;
      oh.w = (base + 3 == bi) ? 1.f : 0.f;
      st4(stoch_out + b * 512 + base, oh);
    }
  }
}

// ---------------- launcher ----------------
extern "C" void kernel_launch(void* const* d_in, const int* in_sizes, int n_in,
                              void* d_out, int out_size, void* d_ws, size_t ws_size,
                              hipStream_t stream) {
  (void)in_sizes; (void)n_in; (void)out_size; (void)ws_size;
  const float* stoch      = (const float*)d_in[0];
  const float* deter      = (const float*)d_in[1];
  const float* action     = (const float*)d_in[2];
  const float* embed      = (const float*)d_in[3];
  const float* in0_w      = (const float*)d_in[4];
  const float* in0_b      = (const float*)d_in[5];
  const float* n0_s       = (const float*)d_in[6];
  const float* in1_w      = (const float*)d_in[7];
  const float* in1_b      = (const float*)d_in[8];
  const float* n1_s       = (const float*)d_in[9];
  const float* in2_w      = (const float*)d_in[10];
  const float* in2_b      = (const float*)d_in[11];
  const float* n2_s       = (const float*)d_in[12];
  const float* hid0_k     = (const float*)d_in[13];
  const float* hid0_b     = (const float*)d_in[14];
  const float* hidn_s     = (const float*)d_in[15];
  const float* gru_k      = (const float*)d_in[16];
  const float* gru_b      = (const float*)d_in[17];
  const float* obs_fc0_w  = (const float*)d_in[18];
  const float* obs_fc0_b  = (const float*)d_in[19];
  const float* obs_n_s    = (const float*)d_in[20];
  const float* obs_out_w  = (const float*)d_in[21];
  const float* obs_out_b  = (const float*)d_in[22];

  float* out = (float*)d_out;
  float* ws  = (float*)d_ws;
  float* wTh  = ws + WS_WTH;
  float* wTg  = ws + WS_WTG;
  float* xb   = ws + WS_X;
  float* xh   = ws + WS_XH;
  float* hb   = ws + WS_H;
  float* part = xh;  // split-K partials overlay xh (dead at both uses)

  hipLaunchKernelGGL(k_transpose2, dim3(448), dim3(256), 0, stream,
                     hid0_k, gru_k, wTh, wTg);
  hipLaunchKernelGGL(k_inproj, dim3(608), dim3(512), 0, stream,
                     deter, stoch, action, in0_w,
                     in1_w, in1_b, n1_s, in2_w, in2_b, n2_s, part, xb);
  hipLaunchKernelGGL(k_combine8, dim3(1024), dim3(256), 0, stream,
                     part, in0_b, n0_s, xb, 768);
  hipLaunchKernelGGL(k_hid0, dim3(512), dim3(512), 0, stream,
                     deter, xb, wTh, hid0_b, xh);
  hipLaunchKernelGGL(k_rmsnorm2048, dim3(4096), dim3(256), 0, stream, xh, hidn_s);
  hipLaunchKernelGGL(k_gru, dim3(512), dim3(512), 0, stream,
                     xh, wTg, gru_b, deter, out + OFF_DETER);
  hipLaunchKernelGGL(k_obsfc0, dim3(512), dim3(512), 0, stream,
                     out + OFF_DETER, embed, obs_fc0_w, part);
  hipLaunchKernelGGL(k_combine8, dim3(1024), dim3(256), 0, stream,
                     part, obs_fc0_b, obs_n_s, hb, 256);
  hipLaunchKernelGGL(k_obs_out, dim3(128), dim3(512), 0, stream,
                     hb, obs_out_w, obs_out_b, out + OFF_LOGIT, out + OFF_STOCH);
}

// Round 4
// 1854.366 us; speedup vs baseline: 3.8141x; 3.8141x over previous
//
#include <hip/hip_runtime.h>
#include <cmath>

// ---------------- problem constants ----------------
constexpr int BATCH = 4096;
constexpr int NG    = 8;
constexpr float EPSN = 1e-4f;

// d_out layout (floats): [new_stoch | new_deter | logit]
constexpr int OFF_STOCH = 0;
constexpr int OFF_DETER = BATCH * 512;
constexpr int OFF_LOGIT = OFF_DETER + BATCH * 2048;

// ws layout (floats)
constexpr size_t WS_WTH = 0;                                // 8*1024*256
constexpr size_t WS_WTG = WS_WTH + (size_t)NG * 1024 * 256; // 8*256*768
constexpr size_t WS_X   = WS_WTG + (size_t)NG * 256 * 768;  // 4096*768
constexpr size_t WS_XH  = WS_X + (size_t)BATCH * 768;       // 4096*2048 (also 8x splitK partials)
constexpr size_t WS_H   = WS_XH + (size_t)BATCH * 2048;     // 4096*256

#define DINLINE __device__ __forceinline__

DINLINE float sigm(float x)  { return 1.0f / (1.0f + expf(-x)); }
DINLINE float siluf(float x) { return x / (1.0f + expf(-x)); }

DINLINE float4 ld4(const float* p) { return *reinterpret_cast<const float4*>(p); }
DINLINE void st4(float* p, float4 v) { *reinterpret_cast<float4*>(p) = v; }

// rmsnorm(256)+silu epilogue: lane holds 4 values of one row, full wave = 256 cols.
DINLINE float4 rms_silu4(float v0, float v1, float v2, float v3, float4 s4) {
  float ss = v0 * v0 + v1 * v1 + v2 * v2 + v3 * v3;
#pragma unroll
  for (int off = 32; off; off >>= 1) ss += __shfl_xor(ss, off);
  float inv = 1.0f / sqrtf(ss * (1.0f / 256.0f) + EPSN);
  float4 o;
  o.x = siluf(v0 * inv * s4.x); o.y = siluf(v1 * inv * s4.y);
  o.z = siluf(v2 * inv * s4.z); o.w = siluf(v3 * inv * s4.w);
  return o;
}

// ---------------- compute core ----------------
// 512 threads, 8 waves. Wave wv owns rows [wv*TM,(wv+1)*TM). Lane owns cols s*256+tx*4.
template<int TM, int TN4, int KC>
DINLINE void mm_chunk(const float* __restrict__ A_s, const float* __restrict__ W_s,
                      float (&acc)[TM][TN4][4], int tx, int wv) {
  constexpr int BN = 256 * TN4;
#pragma unroll
  for (int kk4 = 0; kk4 < KC / 4; ++kk4) {
    float4 w[4][TN4];
#pragma unroll
    for (int j = 0; j < 4; ++j)
#pragma unroll
      for (int s = 0; s < TN4; ++s)
        w[j][s] = ld4(W_s + (kk4 * 4 + j) * BN + s * 256 + tx * 4);
#pragma unroll
    for (int i = 0; i < TM; ++i) {
      float4 a = ld4(A_s + (wv * TM + i) * KC + kk4 * 4);
#pragma unroll
      for (int j = 0; j < 4; ++j) {
        float av = (&a.x)[j];
#pragma unroll
        for (int s = 0; s < TN4; ++s) {
          acc[i][s][0] = fmaf(av, w[j][s].x, acc[i][s][0]);
          acc[i][s][1] = fmaf(av, w[j][s].y, acc[i][s][1]);
          acc[i][s][2] = fmaf(av, w[j][s].z, acc[i][s][2]);
          acc[i][s][3] = fmaf(av, w[j][s].w, acc[i][s][3]);
        }
      }
    }
  }
}

// ---------------- kernel 1: tiled weight transpose ----------------
__global__ __launch_bounds__(256) void k_transpose2(
    const float* __restrict__ hk, const float* __restrict__ gk,
    float* __restrict__ wTh, float* __restrict__ wTg) {
  __shared__ float L[16 * 520];
  const int b = blockIdx.x, t = threadIdx.x;
  const float* src; float* dst; int I, O, o0, i0;
  if (b < 256) { src = hk; dst = wTh; I = 1024; O = 256;
                 int ot = b & 15, it = b >> 4; o0 = ot * 16; i0 = it * 64; }
  else         { src = gk; dst = wTg; I = 256;  O = 768;
                 int b2 = b - 256; int ot = b2 % 48, it = b2 / 48; o0 = ot * 16; i0 = it * 64; }
#pragma unroll
  for (int q = 0; q < 8; ++q) {
    int idx = q * 256 + t;
    int o_l = idx >> 7, rem = idx & 127, i_l = rem >> 1, gh = rem & 1;
    float4 v = ld4(src + ((size_t)(o0 + o_l) * I + i0 + i_l) * 8 + gh * 4);
    st4(&L[o_l * 520 + i_l * 8 + gh * 4], v);
  }
  __syncthreads();
#pragma unroll
  for (int q = 0; q < 8; ++q) {
    int idx = q * 256 + t;
    int g = idx >> 8, rem = idx & 255, i_l = rem >> 2, o4 = rem & 3;
    float4 v;
    v.x = L[(o4 * 4 + 0) * 520 + i_l * 8 + g];
    v.y = L[(o4 * 4 + 1) * 520 + i_l * 8 + g];
    v.z = L[(o4 * 4 + 2) * 520 + i_l * 8 + g];
    v.w = L[(o4 * 4 + 3) * 520 + i_l * 8 + g];
    st4(dst + ((size_t)g * I + i0 + i_l) * O + o0 + o4 * 4, v);
  }
}

// ---------------- pipelined TN4=1 GEMM macro-body ----------------
// BM=64, TM=8, KC=16, BN=256. LDS S[2][64*16 + 16*256].
// A-prefetch is done by threads 0..255 only (64 rows x 16 cols / float4).
#define PIPE_DEFS \
  constexpr int TM = 8, KC = 16, BN = 256; \
  constexpr int AF = 64 * KC, WF = KC * BN; \
  __shared__ float S[2][AF + WF]; \
  const int tid = threadIdx.x, tx = tid & 63, wv = tid >> 6; \
  const int arow = tid >> 2, ac4 = (tid & 3) * 4; \
  float4 wreg0, wreg1, areg; \
  float acc[TM][1][4] = {}; \
  int cur = 0;

#define PIPE_LOADW(Wp, kk) \
  { const float* wp_ = (Wp) + (size_t)(kk) * BN; \
    wreg0 = ld4(wp_ + tid * 4); wreg1 = ld4(wp_ + 2048 + tid * 4); }

#define PIPE_WRITE(buf) \
  { st4(&S[buf][AF + tid * 4], wreg0); st4(&S[buf][AF + 2048 + tid * 4], wreg1); \
    if (tid < 256) st4(&S[buf][arow * KC + ac4], areg); }

// ---------------- kernel 2: input projections (x0 splitK8 | x1 | x2) ----------------
__global__ __launch_bounds__(512) void k_inproj(
    const float* __restrict__ deter, const float* __restrict__ stoch,
    const float* __restrict__ action,
    const float* __restrict__ w0,
    const float* __restrict__ w1, const float* __restrict__ b1, const float* __restrict__ s1,
    const float* __restrict__ w2, const float* __restrict__ b2, const float* __restrict__ s2,
    float* __restrict__ part, float* __restrict__ xb) {
  const int bid = blockIdx.x;
  if (bid >= 576) {  // ---- x2: action (K=17), BM=128 ----
    constexpr int AF2 = 64 * 16 + 16 * 256;
    __shared__ float S2[2][AF2];
    float* W2s = &S2[0][0];          // 17*256 = 4352 <= AF2
    float* A2s = &S2[1][0];          // 128*20 = 2560 <= AF2
    const int tid = threadIdx.x, tx = tid & 63, wv = tid >> 6;
    const int m0 = (bid - 576) * 128;
    for (int e = tid; e < 17 * 256; e += 512) W2s[e] = w2[e];
    for (int e = tid; e < 128 * 17; e += 512) {
      int r = e / 17, c = e % 17;
      float a = action[(size_t)(m0 + r) * 17 + c];
      float m = fabsf(a);
      A2s[r * 20 + c] = a / (m > 1.f ? m : 1.f);
    }
    __syncthreads();
    float4 acc2[16];
#pragma unroll
    for (int r = 0; r < 16; ++r) acc2[r] = make_float4(0.f, 0.f, 0.f, 0.f);
#pragma unroll
    for (int k = 0; k < 17; ++k) {
      float4 w4 = ld4(W2s + k * 256 + tx * 4);
#pragma unroll
      for (int r = 0; r < 16; ++r) {
        float av = A2s[(wv * 16 + r) * 20 + k];
        acc2[r].x = fmaf(av, w4.x, acc2[r].x);
        acc2[r].y = fmaf(av, w4.y, acc2[r].y);
        acc2[r].z = fmaf(av, w4.z, acc2[r].z);
        acc2[r].w = fmaf(av, w4.w, acc2[r].w);
      }
    }
    float4 b4 = ld4(b2 + tx * 4);
    float4 s4 = ld4(s2 + tx * 4);
#pragma unroll
    for (int r = 0; r < 16; ++r) {
      float4 o = rms_silu4(acc2[r].x + b4.x, acc2[r].y + b4.y,
                           acc2[r].z + b4.z, acc2[r].w + b4.w, s4);
      st4(xb + (size_t)(m0 + wv * 16 + r) * 768 + 512 + tx * 4, o);
    }
    return;
  }

  PIPE_DEFS;
  if (bid < 512) {  // ---- x0: deter @ in0_w, split-K 8 ----
    const int ks = bid & 7, m0 = (bid >> 3) * 64, kbase = ks * 256;
    const float* W = w0 + (size_t)kbase * 256;
    PIPE_LOADW(W, 0);
    if (tid < 256) areg = ld4(deter + (size_t)(m0 + arow) * 2048 + kbase + ac4);
    PIPE_WRITE(0);
    __syncthreads();
    for (int t = 0; t < 16; ++t) {
      if (t + 1 < 16) {
        PIPE_LOADW(W, (t + 1) * KC);
        if (tid < 256)
          areg = ld4(deter + (size_t)(m0 + arow) * 2048 + kbase + (t + 1) * KC + ac4);
      }
      mm_chunk<TM, 1, KC>(&S[cur][0], &S[cur][AF], acc, tx, wv);
      if (t + 1 < 16) PIPE_WRITE(cur ^ 1);
      __syncthreads();
      cur ^= 1;
    }
#pragma unroll
    for (int i = 0; i < TM; ++i)
      st4(part + ((size_t)ks * BATCH + m0 + wv * TM + i) * 256 + tx * 4,
          make_float4(acc[i][0][0], acc[i][0][1], acc[i][0][2], acc[i][0][3]));
    return;
  }
  // ---- x1: stoch (K=512) ----
  {
    const int m0 = (bid - 512) * 64;
    PIPE_LOADW(w1, 0);
    if (tid < 256) areg = ld4(stoch + (size_t)(m0 + arow) * 512 + ac4);
    PIPE_WRITE(0);
    __syncthreads();
    for (int t = 0; t < 32; ++t) {
      if (t + 1 < 32) {
        PIPE_LOADW(w1, (t + 1) * KC);
        if (tid < 256)
          areg = ld4(stoch + (size_t)(m0 + arow) * 512 + (t + 1) * KC + ac4);
      }
      mm_chunk<TM, 1, KC>(&S[cur][0], &S[cur][AF], acc, tx, wv);
      if (t + 1 < 32) PIPE_WRITE(cur ^ 1);
      __syncthreads();
      cur ^= 1;
    }
    float4 b4 = ld4(b1 + tx * 4);
    float4 s4 = ld4(s1 + tx * 4);
#pragma unroll
    for (int i = 0; i < TM; ++i) {
      float4 o = rms_silu4(acc[i][0][0] + b4.x, acc[i][0][1] + b4.y,
                           acc[i][0][2] + b4.z, acc[i][0][3] + b4.w, s4);
      st4(xb + (size_t)(m0 + wv * TM + i) * 768 + 256 + tx * 4, o);
    }
  }
}

// ---------------- kernel 3: splitK-8 combine + bias + rmsnorm(256) + silu ----------------
__global__ __launch_bounds__(256) void k_combine8(
    const float* __restrict__ part, const float* __restrict__ bias,
    const float* __restrict__ scale, float* __restrict__ dst, int dstride) {
  const int tid = threadIdx.x, tx = tid & 63, wv = tid >> 6;
  const size_t row = blockIdx.x * 4 + wv;
  float4 v = make_float4(0.f, 0.f, 0.f, 0.f);
#pragma unroll
  for (int p = 0; p < 8; ++p) {
    float4 t = ld4(part + ((size_t)p * BATCH + row) * 256 + tx * 4);
    v.x += t.x; v.y += t.y; v.z += t.z; v.w += t.w;
  }
  float4 b4 = ld4(bias + tx * 4);
  float4 s4 = ld4(scale + tx * 4);
  float4 o = rms_silu4(v.x + b4.x, v.y + b4.y, v.z + b4.z, v.w + b4.w, s4);
  st4(dst + row * dstride + tx * 4, o);
}

// ---------------- kernel 4: hid0 block-linear (+bias) -> xh ----------------
__global__ __launch_bounds__(512) void k_hid0(
    const float* __restrict__ deter, const float* __restrict__ xb,
    const float* __restrict__ wTh, const float* __restrict__ hbias,
    float* __restrict__ yh) {
  PIPE_DEFS;
  const int g = blockIdx.x & 7, m0 = (blockIdx.x >> 3) * 64;
  const float* W = wTh + (size_t)g * 1024 * 256;
  PIPE_LOADW(W, 0);
  if (tid < 256) areg = ld4(deter + (size_t)(m0 + arow) * 2048 + g * 256 + ac4);
  PIPE_WRITE(0);
  __syncthreads();
  for (int t = 0; t < 64; ++t) {
    if (t + 1 < 64) {
      int k = (t + 1) * KC + ac4;
      PIPE_LOADW(W, (t + 1) * KC);
      if (tid < 256)
        areg = (k < 256) ? ld4(deter + (size_t)(m0 + arow) * 2048 + g * 256 + k)
                         : ld4(xb + (size_t)(m0 + arow) * 768 + (k - 256));
    }
    mm_chunk<TM, 1, KC>(&S[cur][0], &S[cur][AF], acc, tx, wv);
    if (t + 1 < 64) PIPE_WRITE(cur ^ 1);
    __syncthreads();
    cur ^= 1;
  }
  float4 b4 = ld4(hbias + g * 256 + tx * 4);
#pragma unroll
  for (int i = 0; i < TM; ++i)
    st4(yh + (size_t)(m0 + wv * TM + i) * 2048 + g * 256 + tx * 4,
        make_float4(acc[i][0][0] + b4.x, acc[i][0][1] + b4.y,
                    acc[i][0][2] + b4.z, acc[i][0][3] + b4.w));
}

// ---------------- kernel 5: in-place rmsnorm(2048)+silu ----------------
__global__ __launch_bounds__(256) void k_rmsnorm2048(
    float* __restrict__ xh, const float* __restrict__ scale) {
  const int b = blockIdx.x, tid = threadIdx.x;
  float* row = xh + (size_t)b * 2048;
  float4 v0 = ld4(row + tid * 8);
  float4 v1 = ld4(row + tid * 8 + 4);
  float ss = v0.x * v0.x + v0.y * v0.y + v0.z * v0.z + v0.w * v0.w +
             v1.x * v1.x + v1.y * v1.y + v1.z * v1.z + v1.w * v1.w;
#pragma unroll
  for (int off = 32; off; off >>= 1) ss += __shfl_xor(ss, off);
  __shared__ float wsum[4];
  if ((tid & 63) == 0) wsum[tid >> 6] = ss;
  __syncthreads();
  float tot = wsum[0] + wsum[1] + wsum[2] + wsum[3];
  float inv = 1.0f / sqrtf(tot * (1.0f / 2048.0f) + EPSN);
  float4 sc0 = ld4(scale + tid * 8);
  float4 sc1 = ld4(scale + tid * 8 + 4);
  float4 o0, o1;
  o0.x = siluf(v0.x * inv * sc0.x); o0.y = siluf(v0.y * inv * sc0.y);
  o0.z = siluf(v0.z * inv * sc0.z); o0.w = siluf(v0.w * inv * sc0.w);
  o1.x = siluf(v1.x * inv * sc1.x); o1.y = siluf(v1.y * inv * sc1.y);
  o1.z = siluf(v1.z * inv * sc1.z); o1.w = siluf(v1.w * inv * sc1.w);
  st4(row + tid * 8, o0);
  st4(row + tid * 8 + 4, o1);
}

// ---------------- kernel 6: gru block-linear + fused GRU -> new_deter ----------------
// BN=768, TN4=3, BM=64, TM=8, KC=16; LDS 2*(1024+12288)*4 = 106.5 KB
__global__ __launch_bounds__(512) void k_gru(
    const float* __restrict__ xh, const float* __restrict__ wTg,
    const float* __restrict__ gb, const float* __restrict__ deter,
    float* __restrict__ newdet) {
  constexpr int TM = 8, KC = 16, BN = 768;
  constexpr int AF = 64 * KC, WF = KC * BN;
  __shared__ float S[2][AF + WF];
  const int tid = threadIdx.x, tx = tid & 63, wv = tid >> 6;
  const int arow = tid >> 2, ac4 = (tid & 3) * 4;
  const int g = blockIdx.x & 7, m0 = (blockIdx.x >> 3) * 64;
  const float* W = wTg + (size_t)g * 256 * 768;
  float4 wr[6]; float4 areg;
  float acc[TM][3][4] = {};
  int cur = 0;
#pragma unroll
  for (int q = 0; q < 6; ++q) wr[q] = ld4(W + (q * 512 + tid) * 4);
  if (tid < 256) areg = ld4(xh + (size_t)(m0 + arow) * 2048 + g * 256 + ac4);
#pragma unroll
  for (int q = 0; q < 6; ++q) st4(&S[0][AF + (q * 512 + tid) * 4], wr[q]);
  if (tid < 256) st4(&S[0][arow * KC + ac4], areg);
  __syncthreads();
  for (int t = 0; t < 16; ++t) {
    if (t + 1 < 16) {
      const float* wp = W + (size_t)(t + 1) * KC * BN;
#pragma unroll
      for (int q = 0; q < 6; ++q) wr[q] = ld4(wp + (q * 512 + tid) * 4);
      if (tid < 256)
        areg = ld4(xh + (size_t)(m0 + arow) * 2048 + g * 256 + (t + 1) * KC + ac4);
    }
    mm_chunk<TM, 3, KC>(&S[cur][0], &S[cur][AF], acc, tx, wv);
    if (t + 1 < 16) {
#pragma unroll
      for (int q = 0; q < 6; ++q) st4(&S[cur ^ 1][AF + (q * 512 + tid) * 4], wr[q]);
      if (tid < 256) st4(&S[cur ^ 1][arow * KC + ac4], areg);
    }
    __syncthreads();
    cur ^= 1;
  }
  const int j0 = tx * 4;
  float4 br = ld4(gb + g * 768 + j0);
  float4 bc = ld4(gb + g * 768 + 256 + j0);
  float4 bu = ld4(gb + g * 768 + 512 + j0);
#pragma unroll
  for (int i = 0; i < TM; ++i) {
    size_t b = m0 + wv * TM + i;
    float4 d = ld4(deter + b * 2048 + g * 256 + j0);
    float4 o;
#pragma unroll
    for (int j = 0; j < 4; ++j) {
      float r = sigm(acc[i][0][j] + (&br.x)[j]);
      float c = acc[i][1][j] + (&bc.x)[j];
      float u = sigm(acc[i][2][j] + (&bu.x)[j] - 1.0f);
      (&o.x)[j] = u * tanhf(r * c) + (1.0f - u) * (&d.x)[j];
    }
    st4(newdet + b * 2048 + g * 256 + j0, o);
  }
}

// ---------------- kernel 7: obs_fc0 splitK-8 partials ----------------
__global__ __launch_bounds__(512) void k_obsfc0(
    const float* __restrict__ newdet, const float* __restrict__ embed,
    const float* __restrict__ W0, float* __restrict__ part) {
  PIPE_DEFS;
  const int ks = blockIdx.x & 7, m0 = (blockIdx.x >> 3) * 64;
  const int kbase = ks * 384;
  const float* W = W0 + (size_t)kbase * 256;
  auto lda = [&](int k) -> float4 {
    int kk = kbase + k + ac4;
    return (kk < 2048) ? ld4(newdet + (size_t)(m0 + arow) * 2048 + kk)
                       : ld4(embed + (size_t)(m0 + arow) * 1024 + (kk - 2048));
  };
  PIPE_LOADW(W, 0);
  if (tid < 256) areg = lda(0);
  PIPE_WRITE(0);
  __syncthreads();
  for (int t = 0; t < 24; ++t) {
    if (t + 1 < 24) {
      PIPE_LOADW(W, (t + 1) * KC);
      if (tid < 256) areg = lda((t + 1) * KC);
    }
    mm_chunk<TM, 1, KC>(&S[cur][0], &S[cur][AF], acc, tx, wv);
    if (t + 1 < 24) PIPE_WRITE(cur ^ 1);
    __syncthreads();
    cur ^= 1;
  }
#pragma unroll
  for (int i = 0; i < TM; ++i)
    st4(part + ((size_t)ks * BATCH + m0 + wv * TM + i) * 256 + tx * 4,
        make_float4(acc[i][0][0], acc[i][0][1], acc[i][0][2], acc[i][0][3]));
}

// ---------------- kernel 8: obs_out -> logit + argmax one-hot ----------------
__global__ __launch_bounds__(512) void k_obs_out(
    const float* __restrict__ h, const float* __restrict__ W0,
    const float* __restrict__ ob, float* __restrict__ logit,
    float* __restrict__ stoch_out) {
  constexpr int TM = 4, KC = 16, BN = 512;
  __shared__ float A_s[32 * KC];
  __shared__ float W_s[KC * BN];
  const int tid = threadIdx.x, tx = tid & 63, wv = tid >> 6;
  const int m0 = blockIdx.x * 32;
  float acc[TM][2][4] = {};
  for (int k0 = 0; k0 < 256; k0 += KC) {
    { int r = tid >> 4, c = tid & 15;
      A_s[r * KC + c] = h[(size_t)(m0 + r) * 256 + k0 + c]; }
#pragma unroll
    for (int q = 0; q < 4; ++q) {
      int e4 = q * 512 + tid;
      st4(W_s + e4 * 4, ld4(W0 + (size_t)k0 * BN + e4 * 4));
    }
    __syncthreads();
    mm_chunk<TM, 2, KC>(A_s, W_s, acc, tx, wv);
    __syncthreads();
  }
  float4 b0 = ld4(ob + tx * 4);
  float4 b1 = ld4(ob + 256 + tx * 4);
#pragma unroll
  for (int i = 0; i < TM; ++i) {
    size_t b = m0 + wv * TM + i;
#pragma unroll
    for (int s = 0; s < 2; ++s) {
      float4 bb = s ? b1 : b0;
      float l0 = acc[i][s][0] + bb.x, l1 = acc[i][s][1] + bb.y;
      float l2 = acc[i][s][2] + bb.z, l3 = acc[i][s][3] + bb.w;
      int base = s * 256 + tx * 4;
      st4(logit + b * 512 + base, make_float4(l0, l1, l2, l3));
      float bv = l0; int bi = base;
      if (l1 > bv) { bv = l1; bi = base + 1; }
      if (l2 > bv) { bv = l2; bi = base + 2; }
      if (l3 > bv) { bv = l3; bi = base + 3; }
#pragma unroll
      for (int off = 1; off <= 2; off <<= 1) {
        float pv = __shfl_xor(bv, off);
        int   pi = __shfl_xor(bi, off);
        if (pv > bv || (pv == bv && pi < bi)) { bv = pv; bi = pi; }
      }
      float4 oh;
      oh.x = (base + 0 == bi) ? 1.f : 0.f;
      oh.y = (base + 1 == bi) ? 1.f : 0.f;
      oh.z = (base + 2 == bi) ? 1.f : 0.f;
      oh.w = (base + 3 == bi) ? 1.f : 0.f;
      st4(stoch_out + b * 512 + base, oh);
    }
  }
}

// ---------------- launcher ----------------
extern "C" void kernel_launch(void* const* d_in, const int* in_sizes, int n_in,
                              void* d_out, int out_size, void* d_ws, size_t ws_size,
                              hipStream_t stream) {
  (void)in_sizes; (void)n_in; (void)out_size; (void)ws_size;
  const float* stoch      = (const float*)d_in[0];
  const float* deter      = (const float*)d_in[1];
  const float* action     = (const float*)d_in[2];
  const float* embed      = (const float*)d_in[3];
  const float* in0_w      = (const float*)d_in[4];
  const float* in0_b      = (const float*)d_in[5];
  const float* n0_s       = (const float*)d_in[6];
  const float* in1_w      = (const float*)d_in[7];
  const float* in1_b      = (const float*)d_in[8];
  const float* n1_s       = (const float*)d_in[9];
  const float* in2_w      = (const float*)d_in[10];
  const float* in2_b      = (const float*)d_in[11];
  const float* n2_s       = (const float*)d_in[12];
  const float* hid0_k     = (const float*)d_in[13];
  const float* hid0_b     = (const float*)d_in[14];
  const float* hidn_s     = (const float*)d_in[15];
  const float* gru_k      = (const float*)d_in[16];
  const float* gru_b      = (const float*)d_in[17];
  const float* obs_fc0_w  = (const float*)d_in[18];
  const float* obs_fc0_b  = (const float*)d_in[19];
  const float* obs_n_s    = (const float*)d_in[20];
  const float* obs_out_w  = (const float*)d_in[21];
  const float* obs_out_b  = (const float*)d_in[22];

  float* out = (float*)d_out;
  float* ws  = (float*)d_ws;
  float* wTh  = ws + WS_WTH;
  float* wTg  = ws + WS_WTG;
  float* xb   = ws + WS_X;
  float* xh   = ws + WS_XH;
  float* hb   = ws + WS_H;
  float* part = xh;  // split-K partials overlay xh (dead at both uses)

  hipLaunchKernelGGL(k_transpose2, dim3(448), dim3(256), 0, stream,
                     hid0_k, gru_k, wTh, wTg);
  hipLaunchKernelGGL(k_inproj, dim3(608), dim3(512), 0, stream,
                     deter, stoch, action, in0_w,
                     in1_w, in1_b, n1_s, in2_w, in2_b, n2_s, part, xb);
  hipLaunchKernelGGL(k_combine8, dim3(1024), dim3(256), 0, stream,
                     part, in0_b, n0_s, xb, 768);
  hipLaunchKernelGGL(k_hid0, dim3(512), dim3(512), 0, stream,
                     deter, xb, wTh, hid0_b, xh);
  hipLaunchKernelGGL(k_rmsnorm2048, dim3(4096), dim3(256), 0, stream, xh, hidn_s);
  hipLaunchKernelGGL(k_gru, dim3(512), dim3(512), 0, stream,
                     xh, wTg, gru_b, deter, out + OFF_DETER);
  hipLaunchKernelGGL(k_obsfc0, dim3(512), dim3(512), 0, stream,
                     out + OFF_DETER, embed, obs_fc0_w, part);
  hipLaunchKernelGGL(k_combine8, dim3(1024), dim3(256), 0, stream,
                     part, obs_fc0_b, obs_n_s, hb, 256);
  hipLaunchKernelGGL(k_obs_out, dim3(128), dim3(512), 0, stream,
                     hb, obs_out_w, obs_out_b, out + OFF_LOGIT, out + OFF_STOCH);
}

// Round 5
// 729.689 us; speedup vs baseline: 9.6927x; 2.5413x over previous
//
#include <hip/hip_runtime.h>
#include <cmath>

// ---------------- problem constants ----------------
constexpr int BATCH = 4096;
constexpr int NG    = 8;
constexpr float EPSN = 1e-4f;

// d_out layout (floats): [new_stoch | new_deter | logit]
constexpr int OFF_STOCH = 0;
constexpr int OFF_DETER = BATCH * 512;
constexpr int OFF_LOGIT = OFF_DETER + BATCH * 2048;

// ws layout (floats)
constexpr size_t WS_WTH = 0;                                // 8*1024*256
constexpr size_t WS_WTG = WS_WTH + (size_t)NG * 1024 * 256; // 8*256*768
constexpr size_t WS_X   = WS_WTG + (size_t)NG * 256 * 768;  // 4096*768
constexpr size_t WS_XH  = WS_X + (size_t)BATCH * 768;       // 4096*2048 (also 8x splitK partials)
constexpr size_t WS_H   = WS_XH + (size_t)BATCH * 2048;     // 4096*256

#define DINLINE __device__ __forceinline__

DINLINE float sigm(float x)  { return 1.0f / (1.0f + expf(-x)); }
DINLINE float siluf(float x) { return x / (1.0f + expf(-x)); }

DINLINE float4 ld4(const float* p) { return *reinterpret_cast<const float4*>(p); }
DINLINE void st4(float* p, float4 v) { *reinterpret_cast<float4*>(p) = v; }

// async HBM->LDS, 16 bytes per lane, no VGPR round-trip.
// LDS dest must be linear in lane order (ours is: byte offset = tid*16).
DINLINE void cp16(float* lds, const float* g) {
  __builtin_amdgcn_global_load_lds(
      (const __attribute__((address_space(1))) unsigned int*)(const void*)g,
      (__attribute__((address_space(3))) unsigned int*)(void*)lds, 16, 0, 0);
}

// rmsnorm(256)+silu epilogue: lane holds 4 values of one row, full wave = 256 cols.
DINLINE float4 rms_silu4(float v0, float v1, float v2, float v3, float4 s4) {
  float ss = v0 * v0 + v1 * v1 + v2 * v2 + v3 * v3;
#pragma unroll
  for (int off = 32; off; off >>= 1) ss += __shfl_xor(ss, off);
  float inv = 1.0f / sqrtf(ss * (1.0f / 256.0f) + EPSN);
  float4 o;
  o.x = siluf(v0 * inv * s4.x); o.y = siluf(v1 * inv * s4.y);
  o.z = siluf(v2 * inv * s4.z); o.w = siluf(v3 * inv * s4.w);
  return o;
}

// ---------------- compute core ----------------
// 512 threads, 8 waves. Wave wv owns rows [wv*TM,(wv+1)*TM). Lane owns cols s*256+tx*4.
template<int TM, int TN4, int KC>
DINLINE void mm_chunk(const float* __restrict__ A_s, const float* __restrict__ W_s,
                      float (&acc)[TM][TN4][4], int tx, int wv) {
  constexpr int BN = 256 * TN4;
#pragma unroll
  for (int kk4 = 0; kk4 < KC / 4; ++kk4) {
    float4 w[4][TN4];
#pragma unroll
    for (int j = 0; j < 4; ++j)
#pragma unroll
      for (int s = 0; s < TN4; ++s)
        w[j][s] = ld4(W_s + (kk4 * 4 + j) * BN + s * 256 + tx * 4);
#pragma unroll
    for (int i = 0; i < TM; ++i) {
      float4 a = ld4(A_s + (wv * TM + i) * KC + kk4 * 4);
#pragma unroll
      for (int j = 0; j < 4; ++j) {
        float av = (&a.x)[j];
#pragma unroll
        for (int s = 0; s < TN4; ++s) {
          acc[i][s][0] = fmaf(av, w[j][s].x, acc[i][s][0]);
          acc[i][s][1] = fmaf(av, w[j][s].y, acc[i][s][1]);
          acc[i][s][2] = fmaf(av, w[j][s].z, acc[i][s][2]);
          acc[i][s][3] = fmaf(av, w[j][s].w, acc[i][s][3]);
        }
      }
    }
  }
}

// ---------------- kernel 1: tiled weight transpose ----------------
__global__ __launch_bounds__(256) void k_transpose2(
    const float* __restrict__ hk, const float* __restrict__ gk,
    float* __restrict__ wTh, float* __restrict__ wTg) {
  __shared__ float L[16 * 520];
  const int b = blockIdx.x, t = threadIdx.x;
  const float* src; float* dst; int I, O, o0, i0;
  if (b < 256) { src = hk; dst = wTh; I = 1024; O = 256;
                 int ot = b & 15, it = b >> 4; o0 = ot * 16; i0 = it * 64; }
  else         { src = gk; dst = wTg; I = 256;  O = 768;
                 int b2 = b - 256; int ot = b2 % 48, it = b2 / 48; o0 = ot * 16; i0 = it * 64; }
#pragma unroll
  for (int q = 0; q < 8; ++q) {
    int idx = q * 256 + t;
    int o_l = idx >> 7, rem = idx & 127, i_l = rem >> 1, gh = rem & 1;
    float4 v = ld4(src + ((size_t)(o0 + o_l) * I + i0 + i_l) * 8 + gh * 4);
    st4(&L[o_l * 520 + i_l * 8 + gh * 4], v);
  }
  __syncthreads();
#pragma unroll
  for (int q = 0; q < 8; ++q) {
    int idx = q * 256 + t;
    int g = idx >> 8, rem = idx & 255, i_l = rem >> 2, o4 = rem & 3;
    float4 v;
    v.x = L[(o4 * 4 + 0) * 520 + i_l * 8 + g];
    v.y = L[(o4 * 4 + 1) * 520 + i_l * 8 + g];
    v.z = L[(o4 * 4 + 2) * 520 + i_l * 8 + g];
    v.w = L[(o4 * 4 + 3) * 520 + i_l * 8 + g];
    st4(dst + ((size_t)g * I + i0 + i_l) * O + o0 + o4 * 4, v);
  }
}

// ---------------- async-pipelined TN4=1 GEMM body ----------------
// BM=64, TM=8, KC=16, BN=256. LDS S[2][64*16 + 16*256] = 40 KB.
// W chunk staged by all 512 threads (2 x cp16); A chunk by threads 0..255 (1 x cp16).
#define PIPE_DEFS \
  constexpr int TM = 8, KC = 16, BN = 256; \
  constexpr int AF = 64 * KC, WF = KC * BN; (void)WF; \
  __shared__ float S[2][AF + 16 * 256]; \
  const int tid = threadIdx.x, tx = tid & 63, wv = tid >> 6; \
  const int arow = tid >> 2, ac4 = (tid & 3) * 4; \
  float acc[TM][1][4] = {}; \
  int cur = 0;

#define PIPE_STAGEW(buf, Wp, kk) \
  { const float* wp_ = (Wp) + (size_t)(kk) * BN; \
    cp16(&S[buf][AF + tid * 4], wp_ + tid * 4); \
    cp16(&S[buf][AF + 2048 + tid * 4], wp_ + 2048 + tid * 4); }

// ---------------- kernel 2: input projections (x0 splitK8 | x1 | x2) ----------------
__global__ __launch_bounds__(512) void k_inproj(
    const float* __restrict__ deter, const float* __restrict__ stoch,
    const float* __restrict__ action,
    const float* __restrict__ w0,
    const float* __restrict__ w1, const float* __restrict__ b1, const float* __restrict__ s1,
    const float* __restrict__ w2, const float* __restrict__ b2, const float* __restrict__ s2,
    float* __restrict__ part, float* __restrict__ xb) {
  const int bid = blockIdx.x;
  if (bid >= 576) {  // ---- x2: action (K=17), BM=128 ----
    __shared__ float W2s[17 * 256];
    __shared__ float A2s[128 * 20];
    const int tid = threadIdx.x, tx = tid & 63, wv = tid >> 6;
    const int m0 = (bid - 576) * 128;
    for (int e = tid; e < 17 * 256; e += 512) W2s[e] = w2[e];
    for (int e = tid; e < 128 * 17; e += 512) {
      int r = e / 17, c = e % 17;
      float a = action[(size_t)(m0 + r) * 17 + c];
      float m = fabsf(a);
      A2s[r * 20 + c] = a / (m > 1.f ? m : 1.f);
    }
    __syncthreads();
    float4 acc2[16];
#pragma unroll
    for (int r = 0; r < 16; ++r) acc2[r] = make_float4(0.f, 0.f, 0.f, 0.f);
#pragma unroll
    for (int k = 0; k < 17; ++k) {
      float4 w4 = ld4(W2s + k * 256 + tx * 4);
#pragma unroll
      for (int r = 0; r < 16; ++r) {
        float av = A2s[(wv * 16 + r) * 20 + k];
        acc2[r].x = fmaf(av, w4.x, acc2[r].x);
        acc2[r].y = fmaf(av, w4.y, acc2[r].y);
        acc2[r].z = fmaf(av, w4.z, acc2[r].z);
        acc2[r].w = fmaf(av, w4.w, acc2[r].w);
      }
    }
    float4 b4 = ld4(b2 + tx * 4);
    float4 s4 = ld4(s2 + tx * 4);
#pragma unroll
    for (int r = 0; r < 16; ++r) {
      float4 o = rms_silu4(acc2[r].x + b4.x, acc2[r].y + b4.y,
                           acc2[r].z + b4.z, acc2[r].w + b4.w, s4);
      st4(xb + (size_t)(m0 + wv * 16 + r) * 768 + 512 + tx * 4, o);
    }
    return;
  }

  PIPE_DEFS;
  if (bid < 512) {  // ---- x0: deter @ in0_w, split-K 8 ----
    const int ks = bid & 7, m0 = (bid >> 3) * 64, kbase = ks * 256;
    const float* W = w0 + (size_t)kbase * 256;
    const float* arowp = deter + (size_t)(m0 + arow) * 2048 + kbase + ac4;
    PIPE_STAGEW(0, W, 0);
    if (tid < 256) cp16(&S[0][tid * 4], arowp);
    __syncthreads();
    for (int t = 0; t < 16; ++t) {
      if (t + 1 < 16) {
        PIPE_STAGEW(cur ^ 1, W, (t + 1) * KC);
        if (tid < 256) cp16(&S[cur ^ 1][tid * 4], arowp + (t + 1) * KC);
      }
      mm_chunk<TM, 1, KC>(&S[cur][0], &S[cur][AF], acc, tx, wv);
      __syncthreads();
      cur ^= 1;
    }
#pragma unroll
    for (int i = 0; i < TM; ++i)
      st4(part + ((size_t)ks * BATCH + m0 + wv * TM + i) * 256 + tx * 4,
          make_float4(acc[i][0][0], acc[i][0][1], acc[i][0][2], acc[i][0][3]));
    return;
  }
  // ---- x1: stoch (K=512) ----
  {
    const int m0 = (bid - 512) * 64;
    const float* arowp = stoch + (size_t)(m0 + arow) * 512 + ac4;
    PIPE_STAGEW(0, w1, 0);
    if (tid < 256) cp16(&S[0][tid * 4], arowp);
    __syncthreads();
    for (int t = 0; t < 32; ++t) {
      if (t + 1 < 32) {
        PIPE_STAGEW(cur ^ 1, w1, (t + 1) * KC);
        if (tid < 256) cp16(&S[cur ^ 1][tid * 4], arowp + (t + 1) * KC);
      }
      mm_chunk<TM, 1, KC>(&S[cur][0], &S[cur][AF], acc, tx, wv);
      __syncthreads();
      cur ^= 1;
    }
    float4 b4 = ld4(b1 + tx * 4);
    float4 s4 = ld4(s1 + tx * 4);
#pragma unroll
    for (int i = 0; i < TM; ++i) {
      float4 o = rms_silu4(acc[i][0][0] + b4.x, acc[i][0][1] + b4.y,
                           acc[i][0][2] + b4.z, acc[i][0][3] + b4.w, s4);
      st4(xb + (size_t)(m0 + wv * TM + i) * 768 + 256 + tx * 4, o);
    }
  }
}

// ---------------- kernel 3: splitK-8 combine + bias + rmsnorm(256) + silu ----------------
__global__ __launch_bounds__(256) void k_combine8(
    const float* __restrict__ part, const float* __restrict__ bias,
    const float* __restrict__ scale, float* __restrict__ dst, int dstride) {
  const int tid = threadIdx.x, tx = tid & 63, wv = tid >> 6;
  const size_t row = blockIdx.x * 4 + wv;
  float4 v = make_float4(0.f, 0.f, 0.f, 0.f);
#pragma unroll
  for (int p = 0; p < 8; ++p) {
    float4 t = ld4(part + ((size_t)p * BATCH + row) * 256 + tx * 4);
    v.x += t.x; v.y += t.y; v.z += t.z; v.w += t.w;
  }
  float4 b4 = ld4(bias + tx * 4);
  float4 s4 = ld4(scale + tx * 4);
  float4 o = rms_silu4(v.x + b4.x, v.y + b4.y, v.z + b4.z, v.w + b4.w, s4);
  st4(dst + row * dstride + tx * 4, o);
}

// ---------------- kernel 4: hid0 block-linear (+bias) -> xh ----------------
__global__ __launch_bounds__(512) void k_hid0(
    const float* __restrict__ deter, const float* __restrict__ xb,
    const float* __restrict__ wTh, const float* __restrict__ hbias,
    float* __restrict__ yh) {
  PIPE_DEFS;
  const int g = blockIdx.x & 7, m0 = (blockIdx.x >> 3) * 64;
  const float* W = wTh + (size_t)g * 1024 * 256;
  const float* dp = deter + (size_t)(m0 + arow) * 2048 + g * 256 + ac4;
  const float* xp = xb + (size_t)(m0 + arow) * 768 + ac4 - 256;
  PIPE_STAGEW(0, W, 0);
  if (tid < 256) cp16(&S[0][tid * 4], dp);
  __syncthreads();
  for (int t = 0; t < 64; ++t) {
    if (t + 1 < 64) {
      int k = (t + 1) * KC;
      PIPE_STAGEW(cur ^ 1, W, k);
      if (tid < 256) cp16(&S[cur ^ 1][tid * 4], (k < 256) ? dp + k : xp + k);
    }
    mm_chunk<TM, 1, KC>(&S[cur][0], &S[cur][AF], acc, tx, wv);
    __syncthreads();
    cur ^= 1;
  }
  float4 b4 = ld4(hbias + g * 256 + tx * 4);
#pragma unroll
  for (int i = 0; i < TM; ++i)
    st4(yh + (size_t)(m0 + wv * TM + i) * 2048 + g * 256 + tx * 4,
        make_float4(acc[i][0][0] + b4.x, acc[i][0][1] + b4.y,
                    acc[i][0][2] + b4.z, acc[i][0][3] + b4.w));
}

// ---------------- kernel 5: in-place rmsnorm(2048)+silu ----------------
__global__ __launch_bounds__(256) void k_rmsnorm2048(
    float* __restrict__ xh, const float* __restrict__ scale) {
  const int b = blockIdx.x, tid = threadIdx.x;
  float* row = xh + (size_t)b * 2048;
  float4 v0 = ld4(row + tid * 8);
  float4 v1 = ld4(row + tid * 8 + 4);
  float ss = v0.x * v0.x + v0.y * v0.y + v0.z * v0.z + v0.w * v0.w +
             v1.x * v1.x + v1.y * v1.y + v1.z * v1.z + v1.w * v1.w;
#pragma unroll
  for (int off = 32; off; off >>= 1) ss += __shfl_xor(ss, off);
  __shared__ float wsum[4];
  if ((tid & 63) == 0) wsum[tid >> 6] = ss;
  __syncthreads();
  float tot = wsum[0] + wsum[1] + wsum[2] + wsum[3];
  float inv = 1.0f / sqrtf(tot * (1.0f / 2048.0f) + EPSN);
  float4 sc0 = ld4(scale + tid * 8);
  float4 sc1 = ld4(scale + tid * 8 + 4);
  float4 o0, o1;
  o0.x = siluf(v0.x * inv * sc0.x); o0.y = siluf(v0.y * inv * sc0.y);
  o0.z = siluf(v0.z * inv * sc0.z); o0.w = siluf(v0.w * inv * sc0.w);
  o1.x = siluf(v1.x * inv * sc1.x); o1.y = siluf(v1.y * inv * sc1.y);
  o1.z = siluf(v1.z * inv * sc1.z); o1.w = siluf(v1.w * inv * sc1.w);
  st4(row + tid * 8, o0);
  st4(row + tid * 8 + 4, o1);
}

// ---------------- kernel 6: gru block-linear + fused GRU -> new_deter ----------------
// BM=64, TM=8, TN4=3, KC=8; LDS 2*(64*8 + 8*768)*4 = 53.25 KB -> 2 blocks/CU.
// All staging via global_load_lds: no staging VGPRs -> acc fits, no spill.
__global__ __launch_bounds__(512) void k_gru(
    const float* __restrict__ xh, const float* __restrict__ wTg,
    const float* __restrict__ gb, const float* __restrict__ deter,
    float* __restrict__ newdet) {
  constexpr int TM = 8, KC = 8, BN = 768;
  constexpr int AF = 64 * KC;
  __shared__ float S[2][AF + KC * BN];
  const int tid = threadIdx.x, tx = tid & 63, wv = tid >> 6;
  const int g = blockIdx.x & 7, m0 = (blockIdx.x >> 3) * 64;
  const float* W = wTg + (size_t)g * 256 * 768;
  const float* ap = xh + (size_t)(m0 + (tid >> 1)) * 2048 + g * 256 + (tid & 1) * 4;
  float acc[TM][3][4] = {};
  int cur = 0;

#define GRU_STAGE(buf, kk) \
  { const float* wp_ = W + (size_t)(kk) * BN; \
    cp16(&S[buf][AF + tid * 4], wp_ + tid * 4); \
    cp16(&S[buf][AF + 2048 + tid * 4], wp_ + 2048 + tid * 4); \
    cp16(&S[buf][AF + 4096 + tid * 4], wp_ + 4096 + tid * 4); \
    if (tid < 128) cp16(&S[buf][tid * 4], ap + (kk)); }

  GRU_STAGE(0, 0);
  __syncthreads();
  for (int t = 0; t < 32; ++t) {
    if (t + 1 < 32) GRU_STAGE(cur ^ 1, (t + 1) * KC);
    mm_chunk<TM, 3, KC>(&S[cur][0], &S[cur][AF], acc, tx, wv);
    __syncthreads();
    cur ^= 1;
  }
#undef GRU_STAGE

  const int j0 = tx * 4;
  float4 br = ld4(gb + g * 768 + j0);
  float4 bc = ld4(gb + g * 768 + 256 + j0);
  float4 bu = ld4(gb + g * 768 + 512 + j0);
#pragma unroll
  for (int i = 0; i < TM; ++i) {
    size_t b = m0 + wv * TM + i;
    float4 d = ld4(deter + b * 2048 + g * 256 + j0);
    float4 o;
#pragma unroll
    for (int j = 0; j < 4; ++j) {
      float r = sigm(acc[i][0][j] + (&br.x)[j]);
      float c = acc[i][1][j] + (&bc.x)[j];
      float u = sigm(acc[i][2][j] + (&bu.x)[j] - 1.0f);
      (&o.x)[j] = u * tanhf(r * c) + (1.0f - u) * (&d.x)[j];
    }
    st4(newdet + b * 2048 + g * 256 + j0, o);
  }
}

// ---------------- kernel 7: obs_fc0 splitK-8 partials ----------------
__global__ __launch_bounds__(512) void k_obsfc0(
    const float* __restrict__ newdet, const float* __restrict__ embed,
    const float* __restrict__ W0, float* __restrict__ part) {
  PIPE_DEFS;
  const int ks = blockIdx.x & 7, m0 = (blockIdx.x >> 3) * 64;
  const int kbase = ks * 384;
  const float* W = W0 + (size_t)kbase * 256;
  PIPE_STAGEW(0, W, 0);
  if (tid < 256) {
    int kk = kbase + ac4;
    const float* ap = (kk < 2048) ? newdet + (size_t)(m0 + arow) * 2048 + kk
                                  : embed + (size_t)(m0 + arow) * 1024 + (kk - 2048);
    cp16(&S[0][tid * 4], ap);
  }
  __syncthreads();
  for (int t = 0; t < 24; ++t) {
    if (t + 1 < 24) {
      PIPE_STAGEW(cur ^ 1, W, (t + 1) * KC);
      if (tid < 256) {
        int kk = kbase + (t + 1) * KC + ac4;
        const float* ap = (kk < 2048) ? newdet + (size_t)(m0 + arow) * 2048 + kk
                                      : embed + (size_t)(m0 + arow) * 1024 + (kk - 2048);
        cp16(&S[cur ^ 1][tid * 4], ap);
      }
    }
    mm_chunk<TM, 1, KC>(&S[cur][0], &S[cur][AF], acc, tx, wv);
    __syncthreads();
    cur ^= 1;
  }
#pragma unroll
  for (int i = 0; i < TM; ++i)
    st4(part + ((size_t)ks * BATCH + m0 + wv * TM + i) * 256 + tx * 4,
        make_float4(acc[i][0][0], acc[i][0][1], acc[i][0][2], acc[i][0][3]));
}

// ---------------- kernel 8: obs_out -> logit + argmax one-hot ----------------
__global__ __launch_bounds__(512) void k_obs_out(
    const float* __restrict__ h, const float* __restrict__ W0,
    const float* __restrict__ ob, float* __restrict__ logit,
    float* __restrict__ stoch_out) {
  constexpr int TM = 4, KC = 16, BN = 512;
  __shared__ float A_s[32 * KC];
  __shared__ float W_s[KC * BN];
  const int tid = threadIdx.x, tx = tid & 63, wv = tid >> 6;
  const int m0 = blockIdx.x * 32;
  float acc[TM][2][4] = {};
  for (int k0 = 0; k0 < 256; k0 += KC) {
    { int r = tid >> 4, c = tid & 15;
      A_s[r * KC + c] = h[(size_t)(m0 + r) * 256 + k0 + c]; }
#pragma unroll
    for (int q = 0; q < 4; ++q) {
      int e4 = q * 512 + tid;
      st4(W_s + e4 * 4, ld4(W0 + (size_t)k0 * BN + e4 * 4));
    }
    __syncthreads();
    mm_chunk<TM, 2, KC>(A_s, W_s, acc, tx, wv);
    __syncthreads();
  }
  float4 b0 = ld4(ob + tx * 4);
  float4 b1 = ld4(ob + 256 + tx * 4);
#pragma unroll
  for (int i = 0; i < TM; ++i) {
    size_t b = m0 + wv * TM + i;
#pragma unroll
    for (int s = 0; s < 2; ++s) {
      float4 bb = s ? b1 : b0;
      float l0 = acc[i][s][0] + bb.x, l1 = acc[i][s][1] + bb.y;
      float l2 = acc[i][s][2] + bb.z, l3 = acc[i][s][3] + bb.w;
      int base = s * 256 + tx * 4;
      st4(logit + b * 512 + base, make_float4(l0, l1, l2, l3));
      float bv = l0; int bi = base;
      if (l1 > bv) { bv = l1; bi = base + 1; }
      if (l2 > bv) { bv = l2; bi = base + 2; }
      if (l3 > bv) { bv = l3; bi = base + 3; }
#pragma unroll
      for (int off = 1; off <= 2; off <<= 1) {
        float pv = __shfl_xor(bv, off);
        int   pi = __shfl_xor(bi, off);
        if (pv > bv || (pv == bv && pi < bi)) { bv = pv; bi = pi; }
      }
      float4 oh;
      oh.x = (base + 0 == bi) ? 1.f : 0.f;
      oh.y = (base + 1 == bi) ? 1.f : 0.f;
      oh.z = (base + 2 == bi) ? 1.f : 0.f;
      oh.w = (base + 3 == bi) ? 1.f : 0.f;
      st4(stoch_out + b * 512 + base, oh);
    }
  }
}

// ---------------- launcher ----------------
extern "C" void kernel_launch(void* const* d_in, const int* in_sizes, int n_in,
                              void* d_out, int out_size, void* d_ws, size_t ws_size,
                              hipStream_t stream) {
  (void)in_sizes; (void)n_in; (void)out_size; (void)ws_size;
  const float* stoch      = (const float*)d_in[0];
  const float* deter      = (const float*)d_in[1];
  const float* action     = (const float*)d_in[2];
  const float* embed      = (const float*)d_in[3];
  const float* in0_w      = (const float*)d_in[4];
  const float* in0_b      = (const float*)d_in[5];
  const float* n0_s       = (const float*)d_in[6];
  const float* in1_w      = (const float*)d_in[7];
  const float* in1_b      = (const float*)d_in[8];
  const float* n1_s       = (const float*)d_in[9];
  const float* in2_w      = (const float*)d_in[10];
  const float* in2_b      = (const float*)d_in[11];
  const float* n2_s       = (const float*)d_in[12];
  const float* hid0_k     = (const float*)d_in[13];
  const float* hid0_b     = (const float*)d_in[14];
  const float* hidn_s     = (const float*)d_in[15];
  const float* gru_k      = (const float*)d_in[16];
  const float* gru_b      = (const float*)d_in[17];
  const float* obs_fc0_w  = (const float*)d_in[18];
  const float* obs_fc0_b  = (const float*)d_in[19];
  const float* obs_n_s    = (const float*)d_in[20];
  const float* obs_out_w  = (const float*)d_in[21];
  const float* obs_out_b  = (const float*)d_in[22];

  float* out = (float*)d_out;
  float* ws  = (float*)d_ws;
  float* wTh  = ws + WS_WTH;
  float* wTg  = ws + WS_WTG;
  float* xb   = ws + WS_X;
  float* xh   = ws + WS_XH;
  float* hb   = ws + WS_H;
  float* part = xh;  // split-K partials overlay xh (dead at both uses)

  hipLaunchKernelGGL(k_transpose2, dim3(448), dim3(256), 0, stream,
                     hid0_k, gru_k, wTh, wTg);
  hipLaunchKernelGGL(k_inproj, dim3(608), dim3(512), 0, stream,
                     deter, stoch, action, in0_w,
                     in1_w, in1_b, n1_s, in2_w, in2_b, n2_s, part, xb);
  hipLaunchKernelGGL(k_combine8, dim3(1024), dim3(256), 0, stream,
                     part, in0_b, n0_s, xb, 768);
  hipLaunchKernelGGL(k_hid0, dim3(512), dim3(512), 0, stream,
                     deter, xb, wTh, hid0_b, xh);
  hipLaunchKernelGGL(k_rmsnorm2048, dim3(4096), dim3(256), 0, stream, xh, hidn_s);
  hipLaunchKernelGGL(k_gru, dim3(512), dim3(512), 0, stream,
                     xh, wTg, gru_b, deter, out + OFF_DETER);
  hipLaunchKernelGGL(k_obsfc0, dim3(512), dim3(512), 0, stream,
                     out + OFF_DETER, embed, obs_fc0_w, part);
  hipLaunchKernelGGL(k_combine8, dim3(1024), dim3(256), 0, stream,
                     part, obs_fc0_b, obs_n_s, hb, 256);
  hipLaunchKernelGGL(k_obs_out, dim3(128), dim3(512), 0, stream,
                     hb, obs_out_w, obs_out_b, out + OFF_LOGIT, out + OFF_STOCH);
}

// Round 6
// 438.386 us; speedup vs baseline: 16.1334x; 1.6645x over previous
//
#include <hip/hip_runtime.h>
#include <cmath>

// ---------------- problem constants ----------------
constexpr int BATCH = 4096;
constexpr float EPSN = 1e-4f;

// d_out layout (floats): [new_stoch | new_deter | logit]
constexpr int OFF_STOCH = 0;
constexpr int OFF_DETER = BATCH * 512;
constexpr int OFF_LOGIT = OFF_DETER + BATCH * 2048;

typedef unsigned short ushort;
typedef __attribute__((ext_vector_type(4))) float f32x4;
typedef __attribute__((ext_vector_type(8))) short s16x8;

#define DINLINE __device__ __forceinline__

DINLINE float sigm(float x)  { return 1.0f / (1.0f + expf(-x)); }
DINLINE float siluf(float x) { return x / (1.0f + expf(-x)); }

DINLINE float4 ld4(const float* p) { return *reinterpret_cast<const float4*>(p); }
DINLINE void st4(float* p, float4 v) { *reinterpret_cast<float4*>(p) = v; }

DINLINE ushort f2bf(float x) {  // RNE f32->bf16 bits
  unsigned u = __float_as_uint(x);
  unsigned r = u + 0x7fffu + ((u >> 16) & 1u);
  return (ushort)(r >> 16);
}
DINLINE float bf2f(ushort h) { return __uint_as_float(((unsigned)h) << 16); }

// async HBM->LDS, 16B/lane; LDS dest linear (base + lane*16)
DINLINE void cp16(float* lds, const float* g) {
  __builtin_amdgcn_global_load_lds(
      (const __attribute__((address_space(1))) unsigned int*)(const void*)g,
      (__attribute__((address_space(3))) unsigned int*)(void*)lds, 16, 0, 0);
}
DINLINE void cp16g(void* lds, const void* g) {
  __builtin_amdgcn_global_load_lds(
      (const __attribute__((address_space(1))) unsigned int*)g,
      (__attribute__((address_space(3))) unsigned int*)lds, 16, 0, 0);
}

DINLINE f32x4 mfma16(s16x8 a, s16x8 b, f32x4 c) {
  return __builtin_amdgcn_mfma_f32_16x16x32_bf16(a, b, c, 0, 0, 0);
}

// XOR-swizzled LDS byte address for [row][64B of k] bf16 tiles. Bijective; <=2-way banks.
DINLINE int swz_addr(int row, int kb0) {
  return (row * 64 + kb0) ^ ((row & 7) << 4);
}
// inverse: given linear dest byte D (16B aligned), recover (row, kb0)
DINLINE void dec_swz(int D, int& row, int& kb) {
  int r2 = (D >> 8) & 1;
  int r0 = ((D >> 6) & 1) ^ r2;
  row = ((D >> 7) << 1) | r0;
  kb = (D & 48) ^ ((row & 3) << 4);
}

// rmsnorm(256)+silu epilogue: lane holds 4 values of one row, full wave = 256 cols.
DINLINE float4 rms_silu4(float v0, float v1, float v2, float v3, float4 s4) {
  float ss = v0 * v0 + v1 * v1 + v2 * v2 + v3 * v3;
#pragma unroll
  for (int off = 32; off; off >>= 1) ss += __shfl_xor(ss, off);
  float inv = 1.0f / sqrtf(ss * (1.0f / 256.0f) + EPSN);
  float4 o;
  o.x = siluf(v0 * inv * s4.x); o.y = siluf(v1 * inv * s4.y);
  o.z = siluf(v2 * inv * s4.z); o.w = siluf(v3 * inv * s4.w);
  return o;
}

// ---------------- f32 compute core (small GEMMs) ----------------
template<int TM, int TN4, int KC>
DINLINE void mm_chunk(const float* __restrict__ A_s, const float* __restrict__ W_s,
                      float (&acc)[TM][TN4][4], int tx, int wv) {
  constexpr int BN = 256 * TN4;
#pragma unroll
  for (int kk4 = 0; kk4 < KC / 4; ++kk4) {
    float4 w[4][TN4];
#pragma unroll
    for (int j = 0; j < 4; ++j)
#pragma unroll
      for (int s = 0; s < TN4; ++s)
        w[j][s] = ld4(W_s + (kk4 * 4 + j) * BN + s * 256 + tx * 4);
#pragma unroll
    for (int i = 0; i < TM; ++i) {
      float4 a = ld4(A_s + (wv * TM + i) * KC + kk4 * 4);
#pragma unroll
      for (int j = 0; j < 4; ++j) {
        float av = (&a.x)[j];
#pragma unroll
        for (int s = 0; s < TN4; ++s) {
          acc[i][s][0] = fmaf(av, w[j][s].x, acc[i][s][0]);
          acc[i][s][1] = fmaf(av, w[j][s].y, acc[i][s][1]);
          acc[i][s][2] = fmaf(av, w[j][s].z, acc[i][s][2]);
          acc[i][s][3] = fmaf(av, w[j][s].w, acc[i][s][3]);
        }
      }
    }
  }
}

// ---------------- kernel 1: weight bf16 hi/lo split + g-deinterleave ----------------
// hk (256,1024,8) -> whh/whl[g][o=256][i=1024]; gk (768,256,8) -> wgh/wgl[g][o=768][i=256]
__global__ __launch_bounds__(256) void k_prep(
    const float* __restrict__ hk, const float* __restrict__ gk,
    ushort* __restrict__ whh, ushort* __restrict__ whl,
    ushort* __restrict__ wgh, ushort* __restrict__ wgl) {
  int t = blockIdx.x * 256 + threadIdx.x;
  const float* src; ushort* dh; ushort* dl; int e, plane;
  if (t < 262144) { e = t; src = hk + (size_t)e * 8; dh = whh; dl = whl; plane = 262144; }
  else { e = t - 262144; src = gk + (size_t)e * 8; dh = wgh; dl = wgl; plane = 196608; }
  float4 v0 = ld4(src), v1 = ld4(src + 4);
  float vv[8] = {v0.x, v0.y, v0.z, v0.w, v1.x, v1.y, v1.z, v1.w};
#pragma unroll
  for (int g2 = 0; g2 < 8; ++g2) {
    ushort h = f2bf(vv[g2]);
    ushort l = f2bf(vv[g2] - bf2f(h));
    dh[(size_t)g2 * plane + e] = h;
    dl[(size_t)g2 * plane + e] = l;
  }
}

// ---------------- kernel 2: hid0 block-linear via split-bf16 MFMA ----------------
// BM=64, BN=256(full), KC=32, 32 k-tiles. 8 waves = 2M x 4N, wave tile 32x64.
__global__ __launch_bounds__(512) void k_hid0m(
    const float* __restrict__ deter, const float* __restrict__ xb,
    const ushort* __restrict__ whh, const ushort* __restrict__ whl,
    const float* __restrict__ hbias, float* __restrict__ yh) {
  __shared__ ushort Ah[64 * 32], Al[64 * 32];          // 4KB each, swizzled
  __shared__ ushort Wh[2][256 * 32], Wl[2][256 * 32];  // 16KB each plane, swizzled
  const int tid = threadIdx.x, lane = tid & 63, wv = tid >> 6;
  const int wr = wv >> 2, wc = wv & 3;
  const int g = blockIdx.x & 7;
  const int m0 = (int)(blockIdx.x >> 3) * 64;

  int wn0, wkb0, wn1, wkb1;
  dec_swz(tid * 16, wn0, wkb0);
  dec_swz(8192 + tid * 16, wn1, wkb1);
  const char* whhB = (const char*)whh + (size_t)g * 256 * 2048;
  const char* whlB = (const char*)whl + (size_t)g * 256 * 2048;

  const int arow = tid >> 2, akq = (tid & 3) * 8;
  const int abyte = swz_addr(arow, (tid & 3) * 16);
  float av[8];

  const f32x4 z4 = {0.f, 0.f, 0.f, 0.f};
  f32x4 acc[2][4];
#pragma unroll
  for (int i = 0; i < 2; ++i)
#pragma unroll
    for (int j = 0; j < 4; ++j) acc[i][j] = z4;

#define H_LOADA(kt) \
  if (tid < 256) { \
    int kg = (kt) * 32 + akq; \
    const float* p = (kg < 256) ? deter + (size_t)(m0 + arow) * 2048 + g * 256 + kg \
                                : xb + (size_t)(m0 + arow) * 768 + (kg - 256); \
    float4 u_ = ld4(p), w_ = ld4(p + 4); \
    av[0] = u_.x; av[1] = u_.y; av[2] = u_.z; av[3] = u_.w; \
    av[4] = w_.x; av[5] = w_.y; av[6] = w_.z; av[7] = w_.w; \
  }
#define H_WRITEA() \
  if (tid < 256) { \
    s16x8 h8, l8; \
    _Pragma("unroll") \
    for (int j = 0; j < 8; ++j) { \
      ushort h_ = f2bf(av[j]); \
      h8[j] = (short)h_; \
      l8[j] = (short)f2bf(av[j] - bf2f(h_)); \
    } \
    *(s16x8*)((char*)Ah + abyte) = h8; \
    *(s16x8*)((char*)Al + abyte) = l8; \
  }
#define H_ISSUEW(buf, kt) { \
    size_t o0_ = (size_t)wn0 * 2048 + (kt) * 64 + wkb0; \
    size_t o1_ = (size_t)wn1 * 2048 + (kt) * 64 + wkb1; \
    cp16g((char*)Wh[buf] + tid * 16, whhB + o0_); \
    cp16g((char*)Wh[buf] + 8192 + tid * 16, whhB + o1_); \
    cp16g((char*)Wl[buf] + tid * 16, whlB + o0_); \
    cp16g((char*)Wl[buf] + 8192 + tid * 16, whlB + o1_); \
  }

  H_LOADA(0);
  H_ISSUEW(0, 0);
  H_WRITEA();
  __syncthreads();
  int cur = 0;
  for (int t = 0; t < 32; ++t) {
    if (t < 31) { H_LOADA(t + 1); H_ISSUEW(cur ^ 1, t + 1); }
    const int k16 = (lane >> 4) * 16;
    s16x8 afh[2], afl[2];
#pragma unroll
    for (int mf = 0; mf < 2; ++mf) {
      int r = wr * 32 + mf * 16 + (lane & 15);
      int by = swz_addr(r, k16);
      afh[mf] = *(const s16x8*)((const char*)Ah + by);
      afl[mf] = *(const s16x8*)((const char*)Al + by);
    }
#pragma unroll
    for (int nf = 0; nf < 4; ++nf) {
      int n = wc * 64 + nf * 16 + (lane & 15);
      int by = swz_addr(n, k16);
      s16x8 bh = *(const s16x8*)((const char*)Wh[cur] + by);
      s16x8 bl = *(const s16x8*)((const char*)Wl[cur] + by);
#pragma unroll
      for (int mf = 0; mf < 2; ++mf) {
        acc[mf][nf] = mfma16(afh[mf], bh, acc[mf][nf]);
        acc[mf][nf] = mfma16(afh[mf], bl, acc[mf][nf]);
        acc[mf][nf] = mfma16(afl[mf], bh, acc[mf][nf]);
      }
    }
    __syncthreads();
    if (t < 31) H_WRITEA();
    __syncthreads();
    cur ^= 1;
  }
#undef H_LOADA
#undef H_WRITEA
#undef H_ISSUEW
  // epilogue: D mapping col=lane&15, row=(lane>>4)*4+r
#pragma unroll
  for (int mf = 0; mf < 2; ++mf) {
    int rbase = m0 + wr * 32 + mf * 16 + ((lane >> 4) << 2);
#pragma unroll
    for (int nf = 0; nf < 4; ++nf) {
      int col = wc * 64 + nf * 16 + (lane & 15);
      float b = hbias[g * 256 + col];
#pragma unroll
      for (int r = 0; r < 4; ++r)
        yh[(size_t)(rbase + r) * 2048 + g * 256 + col] = acc[mf][nf][r] + b;
    }
  }
}

// ---------------- kernel 3: gru block-linear via split-bf16 MFMA + fused GRU ----------------
// BM=128, 64 cols/gate per block (nc in [0,4)), KC=32, 8 k-tiles. waves 2M x 4N.
__global__ __launch_bounds__(512) void k_grum(
    const float* __restrict__ xh,
    const ushort* __restrict__ wgh, const ushort* __restrict__ wgl,
    const float* __restrict__ gb, const float* __restrict__ deter,
    float* __restrict__ newdet) {
  __shared__ ushort Ah[128 * 32], Al[128 * 32];        // 8KB each
  __shared__ ushort Wh[2][192 * 32], Wl[2][192 * 32];  // 12KB each plane
  const int tid = threadIdx.x, lane = tid & 63, wv = tid >> 6;
  const int wr = wv >> 2, wc = wv & 3;
  const int g = blockIdx.x & 7;
  const int nc = (int)(blockIdx.x >> 3) & 3;
  const int m0 = (int)(blockIdx.x >> 5) * 128;

  int wn0, wkb0, wn1, wkb1;
  dec_swz(tid * 16, wn0, wkb0);
  dec_swz(8192 + tid * 16, wn1, wkb1);
  const char* wghB = (const char*)wgh;
  const char* wglB = (const char*)wgl;
  // staged row srow (0..191) -> global o = gate*256 + nc*64 + c; row stride 512B
  const size_t wo0 = (size_t)(g * 768 + ((wn0 >> 6) << 8) + nc * 64 + (wn0 & 63)) * 512 + wkb0;
  const size_t wo1 = (size_t)(g * 768 + ((wn1 >> 6) << 8) + nc * 64 + (wn1 & 63)) * 512 + wkb1;

  const int arow = tid >> 2, akq = (tid & 3) * 8;
  const int abyte = swz_addr(arow, (tid & 3) * 16);
  float av[8];

  const f32x4 z4 = {0.f, 0.f, 0.f, 0.f};
  f32x4 acc[4][3];
#pragma unroll
  for (int i = 0; i < 4; ++i)
#pragma unroll
    for (int j = 0; j < 3; ++j) acc[i][j] = z4;

#define G_LOADA(kt) { \
    const float* p = xh + (size_t)(m0 + arow) * 2048 + g * 256 + (kt) * 32 + akq; \
    float4 u_ = ld4(p), w_ = ld4(p + 4); \
    av[0] = u_.x; av[1] = u_.y; av[2] = u_.z; av[3] = u_.w; \
    av[4] = w_.x; av[5] = w_.y; av[6] = w_.z; av[7] = w_.w; \
  }
#define G_WRITEA() { \
    s16x8 h8, l8; \
    _Pragma("unroll") \
    for (int j = 0; j < 8; ++j) { \
      ushort h_ = f2bf(av[j]); \
      h8[j] = (short)h_; \
      l8[j] = (short)f2bf(av[j] - bf2f(h_)); \
    } \
    *(s16x8*)((char*)Ah + abyte) = h8; \
    *(s16x8*)((char*)Al + abyte) = l8; \
  }
#define G_ISSUEW(buf, kt) { \
    cp16g((char*)Wh[buf] + tid * 16, wghB + wo0 + (kt) * 64); \
    cp16g((char*)Wl[buf] + tid * 16, wglB + wo0 + (kt) * 64); \
    if (tid < 256) { \
      cp16g((char*)Wh[buf] + 8192 + tid * 16, wghB + wo1 + (kt) * 64); \
      cp16g((char*)Wl[buf] + 8192 + tid * 16, wglB + wo1 + (kt) * 64); \
    } \
  }

  G_LOADA(0);
  G_ISSUEW(0, 0);
  G_WRITEA();
  __syncthreads();
  int cur = 0;
  for (int t = 0; t < 8; ++t) {
    if (t < 7) { G_LOADA(t + 1); G_ISSUEW(cur ^ 1, t + 1); }
    const int k16 = (lane >> 4) * 16;
    s16x8 afh[4], afl[4];
#pragma unroll
    for (int mf = 0; mf < 4; ++mf) {
      int r = wr * 64 + mf * 16 + (lane & 15);
      int by = swz_addr(r, k16);
      afh[mf] = *(const s16x8*)((const char*)Ah + by);
      afl[mf] = *(const s16x8*)((const char*)Al + by);
    }
#pragma unroll
    for (int gt = 0; gt < 3; ++gt) {
      int srow = gt * 64 + wc * 16 + (lane & 15);
      int by = swz_addr(srow, k16);
      s16x8 bh = *(const s16x8*)((const char*)Wh[cur] + by);
      s16x8 bl = *(const s16x8*)((const char*)Wl[cur] + by);
#pragma unroll
      for (int mf = 0; mf < 4; ++mf) {
        acc[mf][gt] = mfma16(afh[mf], bh, acc[mf][gt]);
        acc[mf][gt] = mfma16(afh[mf], bl, acc[mf][gt]);
        acc[mf][gt] = mfma16(afl[mf], bh, acc[mf][gt]);
      }
    }
    __syncthreads();
    if (t < 7) G_WRITEA();
    __syncthreads();
    cur ^= 1;
  }
#undef G_LOADA
#undef G_WRITEA
#undef G_ISSUEW
  // fused GRU epilogue in C/D layout
  const int col = nc * 64 + wc * 16 + (lane & 15);
  const float br = gb[g * 768 + col];
  const float bc = gb[g * 768 + 256 + col];
  const float bu = gb[g * 768 + 512 + col];
#pragma unroll
  for (int mf = 0; mf < 4; ++mf) {
    int rbase = m0 + wr * 64 + mf * 16 + ((lane >> 4) << 2);
#pragma unroll
    for (int r = 0; r < 4; ++r) {
      int row = rbase + r;
      float rr = sigm(acc[mf][0][r] + br);
      float cc = acc[mf][1][r] + bc;
      float uu = sigm(acc[mf][2][r] + bu - 1.0f);
      float d = deter[(size_t)row * 2048 + g * 256 + col];
      newdet[(size_t)row * 2048 + g * 256 + col] =
          uu * tanhf(rr * cc) + (1.0f - uu) * d;
    }
  }
}

// ---------------- f32 pipelined TN4=1 GEMM body (small GEMMs, unchanged) ----------------
#define PIPE_DEFS \
  constexpr int TM = 8, KC = 16, BN = 256; \
  constexpr int AF = 64 * KC; \
  __shared__ float S[2][AF + 16 * 256]; \
  const int tid = threadIdx.x, tx = tid & 63, wv = tid >> 6; \
  const int arow = tid >> 2, ac4 = (tid & 3) * 4; \
  float acc[TM][1][4] = {}; \
  int cur = 0;

#define PIPE_STAGEW(buf, Wp, kk) \
  { const float* wp_ = (Wp) + (size_t)(kk) * BN; \
    cp16(&S[buf][AF + tid * 4], wp_ + tid * 4); \
    cp16(&S[buf][AF + 2048 + tid * 4], wp_ + 2048 + tid * 4); }

// ---------------- kernel 4: input projections (x0 splitK8 | x1 | x2) ----------------
__global__ __launch_bounds__(512) void k_inproj(
    const float* __restrict__ deter, const float* __restrict__ stoch,
    const float* __restrict__ action,
    const float* __restrict__ w0,
    const float* __restrict__ w1, const float* __restrict__ b1, const float* __restrict__ s1,
    const float* __restrict__ w2, const float* __restrict__ b2, const float* __restrict__ s2,
    float* __restrict__ part, float* __restrict__ xb) {
  const int bid = blockIdx.x;
  if (bid >= 576) {  // ---- x2: action (K=17), BM=128 ----
    __shared__ float W2s[17 * 256];
    __shared__ float A2s[128 * 20];
    const int tid = threadIdx.x, tx = tid & 63, wv = tid >> 6;
    const int m0 = (bid - 576) * 128;
    for (int e = tid; e < 17 * 256; e += 512) W2s[e] = w2[e];
    for (int e = tid; e < 128 * 17; e += 512) {
      int r = e / 17, c = e % 17;
      float a = action[(size_t)(m0 + r) * 17 + c];
      float m = fabsf(a);
      A2s[r * 20 + c] = a / (m > 1.f ? m : 1.f);
    }
    __syncthreads();
    float4 acc2[16];
#pragma unroll
    for (int r = 0; r < 16; ++r) acc2[r] = make_float4(0.f, 0.f, 0.f, 0.f);
#pragma unroll
    for (int k = 0; k < 17; ++k) {
      float4 w4 = ld4(W2s + k * 256 + tx * 4);
#pragma unroll
      for (int r = 0; r < 16; ++r) {
        float av = A2s[(wv * 16 + r) * 20 + k];
        acc2[r].x = fmaf(av, w4.x, acc2[r].x);
        acc2[r].y = fmaf(av, w4.y, acc2[r].y);
        acc2[r].z = fmaf(av, w4.z, acc2[r].z);
        acc2[r].w = fmaf(av, w4.w, acc2[r].w);
      }
    }
    float4 b4 = ld4(b2 + tx * 4);
    float4 s4 = ld4(s2 + tx * 4);
#pragma unroll
    for (int r = 0; r < 16; ++r) {
      float4 o = rms_silu4(acc2[r].x + b4.x, acc2[r].y + b4.y,
                           acc2[r].z + b4.z, acc2[r].w + b4.w, s4);
      st4(xb + (size_t)(m0 + wv * 16 + r) * 768 + 512 + tx * 4, o);
    }
    return;
  }

  PIPE_DEFS;
  if (bid < 512) {  // ---- x0: deter @ in0_w, split-K 8 ----
    const int ks = bid & 7, m0 = (bid >> 3) * 64, kbase = ks * 256;
    const float* W = w0 + (size_t)kbase * 256;
    const float* arowp = deter + (size_t)(m0 + arow) * 2048 + kbase + ac4;
    PIPE_STAGEW(0, W, 0);
    if (tid < 256) cp16(&S[0][tid * 4], arowp);
    __syncthreads();
    for (int t = 0; t < 16; ++t) {
      if (t + 1 < 16) {
        PIPE_STAGEW(cur ^ 1, W, (t + 1) * KC);
        if (tid < 256) cp16(&S[cur ^ 1][tid * 4], arowp + (t + 1) * KC);
      }
      mm_chunk<TM, 1, KC>(&S[cur][0], &S[cur][AF], acc, tx, wv);
      __syncthreads();
      cur ^= 1;
    }
#pragma unroll
    for (int i = 0; i < TM; ++i)
      st4(part + ((size_t)ks * BATCH + m0 + wv * TM + i) * 256 + tx * 4,
          make_float4(acc[i][0][0], acc[i][0][1], acc[i][0][2], acc[i][0][3]));
    return;
  }
  // ---- x1: stoch (K=512) ----
  {
    const int m0 = (bid - 512) * 64;
    const float* arowp = stoch + (size_t)(m0 + arow) * 512 + ac4;
    PIPE_STAGEW(0, w1, 0);
    if (tid < 256) cp16(&S[0][tid * 4], arowp);
    __syncthreads();
    for (int t = 0; t < 32; ++t) {
      if (t + 1 < 32) {
        PIPE_STAGEW(cur ^ 1, w1, (t + 1) * KC);
        if (tid < 256) cp16(&S[cur ^ 1][tid * 4], arowp + (t + 1) * KC);
      }
      mm_chunk<TM, 1, KC>(&S[cur][0], &S[cur][AF], acc, tx, wv);
      __syncthreads();
      cur ^= 1;
    }
    float4 b4 = ld4(b1 + tx * 4);
    float4 s4 = ld4(s1 + tx * 4);
#pragma unroll
    for (int i = 0; i < TM; ++i) {
      float4 o = rms_silu4(acc[i][0][0] + b4.x, acc[i][0][1] + b4.y,
                           acc[i][0][2] + b4.z, acc[i][0][3] + b4.w, s4);
      st4(xb + (size_t)(m0 + wv * TM + i) * 768 + 256 + tx * 4, o);
    }
  }
}

// ---------------- kernel 5: splitK-8 combine + bias + rmsnorm(256) + silu ----------------
__global__ __launch_bounds__(256) void k_combine8(
    const float* __restrict__ part, const float* __restrict__ bias,
    const float* __restrict__ scale, float* __restrict__ dst, int dstride) {
  const int tid = threadIdx.x, tx = tid & 63, wv = tid >> 6;
  const size_t row = blockIdx.x * 4 + wv;
  float4 v = make_float4(0.f, 0.f, 0.f, 0.f);
#pragma unroll
  for (int p = 0; p < 8; ++p) {
    float4 t = ld4(part + ((size_t)p * BATCH + row) * 256 + tx * 4);
    v.x += t.x; v.y += t.y; v.z += t.z; v.w += t.w;
  }
  float4 b4 = ld4(bias + tx * 4);
  float4 s4 = ld4(scale + tx * 4);
  float4 o = rms_silu4(v.x + b4.x, v.y + b4.y, v.z + b4.z, v.w + b4.w, s4);
  st4(dst + row * dstride + tx * 4, o);
}

// ---------------- kernel 6: in-place rmsnorm(2048)+silu ----------------
__global__ __launch_bounds__(256) void k_rmsnorm2048(
    float* __restrict__ xh, const float* __restrict__ scale) {
  const int b = blockIdx.x, tid = threadIdx.x;
  float* row = xh + (size_t)b * 2048;
  float4 v0 = ld4(row + tid * 8);
  float4 v1 = ld4(row + tid * 8 + 4);
  float ss = v0.x * v0.x + v0.y * v0.y + v0.z * v0.z + v0.w * v0.w +
             v1.x * v1.x + v1.y * v1.y + v1.z * v1.z + v1.w * v1.w;
#pragma unroll
  for (int off = 32; off; off >>= 1) ss += __shfl_xor(ss, off);
  __shared__ float wsum[4];
  if ((tid & 63) == 0) wsum[tid >> 6] = ss;
  __syncthreads();
  float tot = wsum[0] + wsum[1] + wsum[2] + wsum[3];
  float inv = 1.0f / sqrtf(tot * (1.0f / 2048.0f) + EPSN);
  float4 sc0 = ld4(scale + tid * 8);
  float4 sc1 = ld4(scale + tid * 8 + 4);
  float4 o0, o1;
  o0.x = siluf(v0.x * inv * sc0.x); o0.y = siluf(v0.y * inv * sc0.y);
  o0.z = siluf(v0.z * inv * sc0.z); o0.w = siluf(v0.w * inv * sc0.w);
  o1.x = siluf(v1.x * inv * sc1.x); o1.y = siluf(v1.y * inv * sc1.y);
  o1.z = siluf(v1.z * inv * sc1.z); o1.w = siluf(v1.w * inv * sc1.w);
  st4(row + tid * 8, o0);
  st4(row + tid * 8 + 4, o1);
}

// ---------------- kernel 7: obs_fc0 splitK-8 partials ----------------
__global__ __launch_bounds__(512) void k_obsfc0(
    const float* __restrict__ newdet, const float* __restrict__ embed,
    const float* __restrict__ W0, float* __restrict__ part) {
  PIPE_DEFS;
  const int ks = blockIdx.x & 7, m0 = (blockIdx.x >> 3) * 64;
  const int kbase = ks * 384;
  const float* W = W0 + (size_t)kbase * 256;
  auto lda = [&](int k) -> const float* {
    int kk = kbase + k + ac4;
    return (kk < 2048) ? newdet + (size_t)(m0 + arow) * 2048 + kk
                       : embed + (size_t)(m0 + arow) * 1024 + (kk - 2048);
  };
  PIPE_STAGEW(0, W, 0);
  if (tid < 256) cp16(&S[0][tid * 4], lda(0));
  __syncthreads();
  for (int t = 0; t < 24; ++t) {
    if (t + 1 < 24) {
      PIPE_STAGEW(cur ^ 1, W, (t + 1) * KC);
      if (tid < 256) cp16(&S[cur ^ 1][tid * 4], lda((t + 1) * KC));
    }
    mm_chunk<TM, 1, KC>(&S[cur][0], &S[cur][AF], acc, tx, wv);
    __syncthreads();
    cur ^= 1;
  }
#pragma unroll
  for (int i = 0; i < TM; ++i)
    st4(part + ((size_t)ks * BATCH + m0 + wv * TM + i) * 256 + tx * 4,
        make_float4(acc[i][0][0], acc[i][0][1], acc[i][0][2], acc[i][0][3]));
}

// ---------------- kernel 8: obs_out -> logit + argmax one-hot ----------------
__global__ __launch_bounds__(512) void k_obs_out(
    const float* __restrict__ h, const float* __restrict__ W0,
    const float* __restrict__ ob, float* __restrict__ logit,
    float* __restrict__ stoch_out) {
  constexpr int TM = 4, KC = 16, BN = 512;
  __shared__ float A_s[32 * KC];
  __shared__ float W_s[KC * BN];
  const int tid = threadIdx.x, tx = tid & 63, wv = tid >> 6;
  const int m0 = blockIdx.x * 32;
  float acc[TM][2][4] = {};
  for (int k0 = 0; k0 < 256; k0 += KC) {
    { int r = tid >> 4, c = tid & 15;
      A_s[r * KC + c] = h[(size_t)(m0 + r) * 256 + k0 + c]; }
#pragma unroll
    for (int q = 0; q < 4; ++q) {
      int e4 = q * 512 + tid;
      st4(W_s + e4 * 4, ld4(W0 + (size_t)k0 * BN + e4 * 4));
    }
    __syncthreads();
    mm_chunk<TM, 2, KC>(A_s, W_s, acc, tx, wv);
    __syncthreads();
  }
  float4 b0 = ld4(ob + tx * 4);
  float4 b1 = ld4(ob + 256 + tx * 4);
#pragma unroll
  for (int i = 0; i < TM; ++i) {
    size_t b = m0 + wv * TM + i;
#pragma unroll
    for (int s = 0; s < 2; ++s) {
      float4 bb = s ? b1 : b0;
      float l0 = acc[i][s][0] + bb.x, l1 = acc[i][s][1] + bb.y;
      float l2 = acc[i][s][2] + bb.z, l3 = acc[i][s][3] + bb.w;
      int base = s * 256 + tx * 4;
      st4(logit + b * 512 + base, make_float4(l0, l1, l2, l3));
      float bv = l0; int bi = base;
      if (l1 > bv) { bv = l1; bi = base + 1; }
      if (l2 > bv) { bv = l2; bi = base + 2; }
      if (l3 > bv) { bv = l3; bi = base + 3; }
#pragma unroll
      for (int off = 1; off <= 2; off <<= 1) {
        float pv = __shfl_xor(bv, off);
        int   pi = __shfl_xor(bi, off);
        if (pv > bv || (pv == bv && pi < bi)) { bv = pv; bi = pi; }
      }
      float4 oh;
      oh.x = (base + 0 == bi) ? 1.f : 0.f;
      oh.y = (base + 1 == bi) ? 1.f : 0.f;
      oh.z = (base + 2 == bi) ? 1.f : 0.f;
      oh.w = (base + 3 == bi) ? 1.f : 0.f;
      st4(stoch_out + b * 512 + base, oh);
    }
  }
}

// ---------------- launcher ----------------
extern "C" void kernel_launch(void* const* d_in, const int* in_sizes, int n_in,
                              void* d_out, int out_size, void* d_ws, size_t ws_size,
                              hipStream_t stream) {
  (void)in_sizes; (void)n_in; (void)out_size; (void)ws_size;
  const float* stoch      = (const float*)d_in[0];
  const float* deter      = (const float*)d_in[1];
  const float* action     = (const float*)d_in[2];
  const float* embed      = (const float*)d_in[3];
  const float* in0_w      = (const float*)d_in[4];
  const float* in0_b      = (const float*)d_in[5];
  const float* n0_s       = (const float*)d_in[6];
  const float* in1_w      = (const float*)d_in[7];
  const float* in1_b      = (const float*)d_in[8];
  const float* n1_s       = (const float*)d_in[9];
  const float* in2_w      = (const float*)d_in[10];
  const float* in2_b      = (const float*)d_in[11];
  const float* n2_s       = (const float*)d_in[12];
  const float* hid0_k     = (const float*)d_in[13];
  const float* hid0_b     = (const float*)d_in[14];
  const float* hidn_s     = (const float*)d_in[15];
  const float* gru_k      = (const float*)d_in[16];
  const float* gru_b      = (const float*)d_in[17];
  const float* obs_fc0_w  = (const float*)d_in[18];
  const float* obs_fc0_b  = (const float*)d_in[19];
  const float* obs_n_s    = (const float*)d_in[20];
  const float* obs_out_w  = (const float*)d_in[21];
  const float* obs_out_b  = (const float*)d_in[22];

  float* out = (float*)d_out;
  float* ws  = (float*)d_ws;
  // bf16 weight planes
  ushort* whh = (ushort*)ws;                 // 8*256*1024
  ushort* whl = whh + 2097152;
  ushort* wgh = whl + 2097152;               // 8*768*256
  ushort* wgl = wgh + 1572864;
  float*  xb  = ws + 3670016;                // 4096*768
  float*  xh  = xb + (size_t)4096 * 768;     // 4096*2048
  float*  hb  = xh + (size_t)4096 * 2048;    // 4096*256
  float*  part = xh;                         // splitK partials overlay xh (dead at both uses)

  hipLaunchKernelGGL(k_prep, dim3(1792), dim3(256), 0, stream,
                     hid0_k, gru_k, whh, whl, wgh, wgl);
  hipLaunchKernelGGL(k_inproj, dim3(608), dim3(512), 0, stream,
                     deter, stoch, action, in0_w,
                     in1_w, in1_b, n1_s, in2_w, in2_b, n2_s, part, xb);
  hipLaunchKernelGGL(k_combine8, dim3(1024), dim3(256), 0, stream,
                     part, in0_b, n0_s, xb, 768);
  hipLaunchKernelGGL(k_hid0m, dim3(512), dim3(512), 0, stream,
                     deter, xb, whh, whl, hid0_b, xh);
  hipLaunchKernelGGL(k_rmsnorm2048, dim3(4096), dim3(256), 0, stream, xh, hidn_s);
  hipLaunchKernelGGL(k_grum, dim3(1024), dim3(512), 0, stream,
                     xh, wgh, wgl, gru_b, deter, out + OFF_DETER);
  hipLaunchKernelGGL(k_obsfc0, dim3(512), dim3(512), 0, stream,
                     out + OFF_DETER, embed, obs_fc0_w, part);
  hipLaunchKernelGGL(k_combine8, dim3(1024), dim3(256), 0, stream,
                     part, obs_fc0_b, obs_n_s, hb, 256);
  hipLaunchKernelGGL(k_obs_out, dim3(128), dim3(512), 0, stream,
                     hb, obs_out_w, obs_out_b, out + OFF_LOGIT, out + OFF_STOCH);
}

// Round 8
// 270.615 us; speedup vs baseline: 26.1355x; 1.6200x over previous
//
#include <hip/hip_runtime.h>
#include <cmath>

// ---------------- problem constants ----------------
constexpr int BATCH = 4096;
constexpr float EPSN = 1e-4f;

// d_out layout (floats): [new_stoch | new_deter | logit]
constexpr int OFF_STOCH = 0;
constexpr int OFF_DETER = BATCH * 512;
constexpr int OFF_LOGIT = OFF_DETER + BATCH * 2048;

typedef unsigned short ushort;
typedef __attribute__((ext_vector_type(4))) float f32x4;
typedef __attribute__((ext_vector_type(8))) short s16x8;

// ---------------- ws layout ----------------
// PROVEN BUDGET: rounds 1-6 all ran at 62.0 MiB; round 7 failed at 68 MiB
// (hb out-of-bounds -> garbage logits). Keep total <= 62.0 MiB.
// Persistent bf16 planes (ushort offsets):
constexpr size_t U_WHH = 0;                      // hid hi  [g][256][1024]
constexpr size_t U_WHL = U_WHH + 2097152;        // hid lo
constexpr size_t U_WGH = U_WHL + 2097152;        // gru hi  [g][768][256]
constexpr size_t U_WGL = U_WGH + 1572864;        // gru lo
constexpr size_t U_WFH = U_WGL + 1572864;        // obs_fc0 hi [256][3072]
constexpr size_t U_WFL = U_WFH + 786432;
constexpr size_t U_WOH = U_WFL + 786432;         // obs_out hi [512][256]
constexpr size_t U_WOL = U_WOH + 131072;
constexpr size_t U_PEND = U_WOL + 131072;        // 9,175,040 ushorts
// f32 offsets:
constexpr size_t F_XB = U_PEND / 2;              // 4,587,520  (4096x768)
constexpr size_t F_XH = F_XB + 3145728;          // 7,733,248  (4096x2048; also partials)
// total = F_XH + 8,388,608 = 16,121,856 f32 = 61.5 MiB
// Transient w0/w1 planes live in xh tail (dead before k_hid0m writes xh).
// Mode-0 partials use only xh[0, 3*4096*512) = first 6,291,456 f32.
constexpr size_t U_X0H = (F_XH + 6291456) * 2;   // in0_w hi [256][2048]
constexpr size_t U_X0L = U_X0H + 524288;
constexpr size_t U_X1H = U_X0L + 524288;         // in1_w hi [256][512]
constexpr size_t U_X1L = U_X1H + 131072;         // ends at f32 14,680,064 < 16,121,856
// hb lives in xh after mode-1 partials (4 x 4096 x 256 = 4,194,304 f32).
constexpr size_t F_HB = F_XH + 4194304;

#define DINLINE __device__ __forceinline__

DINLINE float sigm(float x)  { return 1.0f / (1.0f + expf(-x)); }
DINLINE float siluf(float x) { return x / (1.0f + expf(-x)); }

DINLINE float4 ld4(const float* p) { return *reinterpret_cast<const float4*>(p); }
DINLINE void st4(float* p, float4 v) { *reinterpret_cast<float4*>(p) = v; }

DINLINE ushort f2bf(float x) {  // RNE f32->bf16 bits
  unsigned u = __float_as_uint(x);
  unsigned r = u + 0x7fffu + ((u >> 16) & 1u);
  return (ushort)(r >> 16);
}
DINLINE float bf2f(ushort h) { return __uint_as_float(((unsigned)h) << 16); }

DINLINE void cp16g(void* lds, const void* g) {
  __builtin_amdgcn_global_load_lds(
      (const __attribute__((address_space(1))) unsigned int*)g,
      (__attribute__((address_space(3))) unsigned int*)lds, 16, 0, 0);
}

DINLINE f32x4 mfma16(s16x8 a, s16x8 b, f32x4 c) {
  return __builtin_amdgcn_mfma_f32_16x16x32_bf16(a, b, c, 0, 0, 0);
}

// XOR-swizzled LDS byte address for [row][64B of k] bf16 tiles (validated round 6).
DINLINE int swz_addr(int row, int kb0) {
  return (row * 64 + kb0) ^ ((row & 7) << 4);
}
DINLINE void dec_swz(int D, int& row, int& kb) {
  int r2 = (D >> 8) & 1;
  int r0 = ((D >> 6) & 1) ^ r2;
  row = ((D >> 7) << 1) | r0;
  kb = (D & 48) ^ ((row & 3) << 4);
}

// rmsnorm(256)+silu epilogue: lane holds 4 values of one row, full wave = 256 cols.
DINLINE float4 rms_silu4(float v0, float v1, float v2, float v3, float4 s4) {
  float ss = v0 * v0 + v1 * v1 + v2 * v2 + v3 * v3;
#pragma unroll
  for (int off = 32; off; off >>= 1) ss += __shfl_xor(ss, off);
  float inv = 1.0f / sqrtf(ss * (1.0f / 256.0f) + EPSN);
  float4 o;
  o.x = siluf(v0 * inv * s4.x); o.y = siluf(v1 * inv * s4.y);
  o.z = siluf(v2 * inv * s4.z); o.w = siluf(v3 * inv * s4.w);
  return o;
}

// ---------------- kernel 1: weight prep ----------------
__global__ __launch_bounds__(256) void k_prep(
    const float* __restrict__ hk, const float* __restrict__ gk,
    const float* __restrict__ w0, const float* __restrict__ w1,
    const float* __restrict__ wf, const float* __restrict__ wo,
    ushort* __restrict__ wsU) {
  __shared__ float L[64 * 65];
  const int bid = blockIdx.x, tid = threadIdx.x;
  if (bid < 1792) {
    int t = bid * 256 + tid;
    const float* src; ushort* dh; ushort* dl; int e, plane;
    if (t < 262144) { e = t; src = hk + (size_t)e * 8; dh = wsU + U_WHH; dl = wsU + U_WHL; plane = 262144; }
    else { e = t - 262144; src = gk + (size_t)e * 8; dh = wsU + U_WGH; dl = wsU + U_WGL; plane = 196608; }
    float4 v0 = ld4(src), v1 = ld4(src + 4);
    float vv[8] = {v0.x, v0.y, v0.z, v0.w, v1.x, v1.y, v1.z, v1.w};
#pragma unroll
    for (int g2 = 0; g2 < 8; ++g2) {
      ushort h = f2bf(vv[g2]);
      ushort l = f2bf(vv[g2] - bf2f(h));
      dh[(size_t)g2 * plane + e] = h;
      dl[(size_t)g2 * plane + e] = l;
    }
    return;
  }
  int t = bid - 1792;
  const float* src; ushort* dh; ushort* dl; int K, N;
  if (t < 128)      { src = w0; dh = wsU + U_X0H; dl = wsU + U_X0L; K = 2048; N = 256; }
  else if (t < 160) { t -= 128; src = w1; dh = wsU + U_X1H; dl = wsU + U_X1L; K = 512;  N = 256; }
  else if (t < 352) { t -= 160; src = wf; dh = wsU + U_WFH; dl = wsU + U_WFL; K = 3072; N = 256; }
  else              { t -= 352; src = wo; dh = wsU + U_WOH; dl = wsU + U_WOL; K = 256;  N = 512; }
  const int ntiles = N / 64;
  const int k0 = (t / ntiles) * 64, n0 = (t % ntiles) * 64;
#pragma unroll
  for (int q = 0; q < 4; ++q) {
    int row = q * 16 + (tid >> 4), col = (tid & 15) * 4;
    float4 v = ld4(src + (size_t)(k0 + row) * N + n0 + col);
    L[row * 65 + col]     = v.x;
    L[row * 65 + col + 1] = v.y;
    L[row * 65 + col + 2] = v.z;
    L[row * 65 + col + 3] = v.w;
  }
  __syncthreads();
  const int n = tid >> 2, kc = (tid & 3) * 16;
  s16x8 h0, h1, l0v, l1v;
#pragma unroll
  for (int j = 0; j < 16; ++j) {
    float x = L[(kc + j) * 65 + n];
    ushort h = f2bf(x);
    ushort l = f2bf(x - bf2f(h));
    if (j < 8) { h0[j] = (short)h; l0v[j] = (short)l; }
    else       { h1[j - 8] = (short)h; l1v[j - 8] = (short)l; }
  }
  size_t ob = (size_t)(n0 + n) * K + k0 + kc;
  *(s16x8*)(dh + ob)     = h0;
  *(s16x8*)(dh + ob + 8) = h1;
  *(s16x8*)(dl + ob)     = l0v;
  *(s16x8*)(dl + ob + 8) = l1v;
}

// ---------------- unified split-bf16 MFMA GEMM (BM=64, BN=256, KC=32) ----------------
// mode 0 (grid 384): bid<256 -> x0 (deter @ w0, splitK4, partials packed 2/plane);
//                    else     -> x1 (stoch @ w1, splitK2, plane 2 halves)
// mode 1 (grid 256): obsfc0 (concat(newdet,embed) @ wf, splitK4)
__global__ __launch_bounds__(512) void k_gemm256(
    int mode,
    const float* __restrict__ deter, const float* __restrict__ stoch,
    const float* __restrict__ newdet, const float* __restrict__ embed,
    const ushort* __restrict__ wsU, float* __restrict__ part) {
  __shared__ ushort Ah[64 * 32], Al[64 * 32];
  __shared__ ushort Wh[2][256 * 32], Wl[2][256 * 32];
  const int tid = threadIdx.x, lane = tid & 63, wv = tid >> 6;
  const int wr = wv >> 2, wc = wv & 3;
  const int bid = blockIdx.x;
  constexpr size_t PL0 = (size_t)4096 * 512;

  const float* A0; const float* A1 = nullptr;
  int lda0, lda1 = 0, ksw = 1 << 30;
  const ushort* whp; const ushort* wlp;
  int KwB, kbase, KT, m0, dstride, dcol;
  float* dst;

  if (mode == 0) {
    if (bid < 256) {
      int ks = bid & 3; m0 = (bid >> 2) * 64; kbase = ks * 512; KT = 16;
      A0 = deter; lda0 = 2048;
      whp = wsU + U_X0H; wlp = wsU + U_X0L; KwB = 4096;
      dst = part + (size_t)(ks >> 1) * PL0; dstride = 512; dcol = (ks & 1) * 256;
    } else {
      int b = bid - 256; int ks = b & 1; m0 = (b >> 1) * 64; kbase = ks * 256; KT = 8;
      A0 = stoch; lda0 = 512;
      whp = wsU + U_X1H; wlp = wsU + U_X1L; KwB = 1024;
      dst = part + 2 * PL0; dstride = 512; dcol = ks * 256;
    }
  } else {
    int ks = bid & 3; m0 = (bid >> 2) * 64; kbase = ks * 768; KT = 24;
    A0 = newdet; lda0 = 2048; A1 = embed; lda1 = 1024; ksw = 2048;
    whp = wsU + U_WFH; wlp = wsU + U_WFL; KwB = 6144;
    dst = part + (size_t)ks * 4096 * 256; dstride = 256; dcol = 0;
  }

  int wn0, wkb0, wn1, wkb1;
  dec_swz(tid * 16, wn0, wkb0);
  dec_swz(8192 + tid * 16, wn1, wkb1);
  const char* whB = (const char*)whp;
  const char* wlB = (const char*)wlp;
  const size_t wo0 = (size_t)wn0 * KwB + kbase * 2 + wkb0;
  const size_t wo1 = (size_t)wn1 * KwB + kbase * 2 + wkb1;

  const int arow = tid >> 2, akq = (tid & 3) * 8;
  const int abyte = swz_addr(arow, (tid & 3) * 16);
  float av[8];

  const f32x4 z4 = {0.f, 0.f, 0.f, 0.f};
  f32x4 acc[2][4];
#pragma unroll
  for (int i = 0; i < 2; ++i)
#pragma unroll
    for (int j = 0; j < 4; ++j) acc[i][j] = z4;

#define U_LOADA(kt) \
  if (tid < 256) { \
    int kg = kbase + (kt) * 32 + akq; \
    const float* p = (kg < ksw) ? A0 + (size_t)(m0 + arow) * lda0 + kg \
                                : A1 + (size_t)(m0 + arow) * lda1 + (kg - ksw); \
    float4 u_ = ld4(p), w_ = ld4(p + 4); \
    av[0] = u_.x; av[1] = u_.y; av[2] = u_.z; av[3] = u_.w; \
    av[4] = w_.x; av[5] = w_.y; av[6] = w_.z; av[7] = w_.w; \
  }
#define U_WRITEA() \
  if (tid < 256) { \
    s16x8 h8, l8; \
    _Pragma("unroll") \
    for (int j = 0; j < 8; ++j) { \
      ushort h_ = f2bf(av[j]); \
      h8[j] = (short)h_; \
      l8[j] = (short)f2bf(av[j] - bf2f(h_)); \
    } \
    *(s16x8*)((char*)Ah + abyte) = h8; \
    *(s16x8*)((char*)Al + abyte) = l8; \
  }
#define U_ISSUEW(buf, kt) { \
    cp16g((char*)Wh[buf] + tid * 16, whB + wo0 + (kt) * 64); \
    cp16g((char*)Wh[buf] + 8192 + tid * 16, whB + wo1 + (kt) * 64); \
    cp16g((char*)Wl[buf] + tid * 16, wlB + wo0 + (kt) * 64); \
    cp16g((char*)Wl[buf] + 8192 + tid * 16, wlB + wo1 + (kt) * 64); \
  }

  U_LOADA(0);
  U_ISSUEW(0, 0);
  U_WRITEA();
  __syncthreads();
  int cur = 0;
  for (int t = 0; t < KT; ++t) {
    if (t + 1 < KT) { U_LOADA(t + 1); U_ISSUEW(cur ^ 1, t + 1); }
    const int k16 = (lane >> 4) * 16;
    s16x8 afh[2], afl[2];
#pragma unroll
    for (int mf = 0; mf < 2; ++mf) {
      int by = swz_addr(wr * 32 + mf * 16 + (lane & 15), k16);
      afh[mf] = *(const s16x8*)((const char*)Ah + by);
      afl[mf] = *(const s16x8*)((const char*)Al + by);
    }
#pragma unroll
    for (int nf = 0; nf < 4; ++nf) {
      int by = swz_addr(wc * 64 + nf * 16 + (lane & 15), k16);
      s16x8 bh = *(const s16x8*)((const char*)Wh[cur] + by);
      s16x8 bl = *(const s16x8*)((const char*)Wl[cur] + by);
#pragma unroll
      for (int mf = 0; mf < 2; ++mf) {
        acc[mf][nf] = mfma16(afh[mf], bh, acc[mf][nf]);
        acc[mf][nf] = mfma16(afh[mf], bl, acc[mf][nf]);
        acc[mf][nf] = mfma16(afl[mf], bh, acc[mf][nf]);
      }
    }
    __syncthreads();
    if (t + 1 < KT) U_WRITEA();
    __syncthreads();
    cur ^= 1;
  }
#undef U_LOADA
#undef U_WRITEA
#undef U_ISSUEW
#pragma unroll
  for (int mf = 0; mf < 2; ++mf) {
    int rbase = m0 + wr * 32 + mf * 16 + ((lane >> 4) << 2);
#pragma unroll
    for (int nf = 0; nf < 4; ++nf) {
      int col = dcol + wc * 64 + nf * 16 + (lane & 15);
#pragma unroll
      for (int r = 0; r < 4; ++r)
        dst[(size_t)(rbase + r) * dstride + col] = acc[mf][nf][r];
    }
  }
}

// ---------------- x2: action (K=17) f32 projection + rmsnorm + silu ----------------
__global__ __launch_bounds__(512) void k_x2(
    const float* __restrict__ action, const float* __restrict__ w2,
    const float* __restrict__ b2, const float* __restrict__ s2,
    float* __restrict__ xb) {
  __shared__ float W2s[17 * 256];
  __shared__ float A2s[128 * 20];
  const int tid = threadIdx.x, tx = tid & 63, wv = tid >> 6;
  const int m0 = blockIdx.x * 128;
  for (int e = tid; e < 17 * 256; e += 512) W2s[e] = w2[e];
  for (int e = tid; e < 128 * 17; e += 512) {
    int r = e / 17, c = e % 17;
    float a = action[(size_t)(m0 + r) * 17 + c];
    float m = fabsf(a);
    A2s[r * 20 + c] = a / (m > 1.f ? m : 1.f);
  }
  __syncthreads();
  float4 acc2[16];
#pragma unroll
  for (int r = 0; r < 16; ++r) acc2[r] = make_float4(0.f, 0.f, 0.f, 0.f);
#pragma unroll
  for (int k = 0; k < 17; ++k) {
    float4 w4 = ld4(W2s + k * 256 + tx * 4);
#pragma unroll
    for (int r = 0; r < 16; ++r) {
      float av = A2s[(wv * 16 + r) * 20 + k];
      acc2[r].x = fmaf(av, w4.x, acc2[r].x);
      acc2[r].y = fmaf(av, w4.y, acc2[r].y);
      acc2[r].z = fmaf(av, w4.z, acc2[r].z);
      acc2[r].w = fmaf(av, w4.w, acc2[r].w);
    }
  }
  float4 b4 = ld4(b2 + tx * 4);
  float4 s4 = ld4(s2 + tx * 4);
#pragma unroll
  for (int r = 0; r < 16; ++r) {
    float4 o = rms_silu4(acc2[r].x + b4.x, acc2[r].y + b4.y,
                         acc2[r].z + b4.z, acc2[r].w + b4.w, s4);
    st4(xb + (size_t)(m0 + wv * 16 + r) * 768 + 512 + tx * 4, o);
  }
}

// ---------------- combine: x0 (planes 0,1 col-halves) | x1 (plane 2) ----------------
__global__ __launch_bounds__(256) void k_comb_in(
    const float* __restrict__ part,
    const float* __restrict__ b0, const float* __restrict__ s0,
    const float* __restrict__ b1, const float* __restrict__ s1,
    float* __restrict__ xb) {
  const int tid = threadIdx.x, tx = tid & 63, wv = tid >> 6;
  const size_t row = blockIdx.x * 2 + (wv >> 1);
  const int half = wv & 1;
  constexpr size_t PL = (size_t)4096 * 512;
  float4 v = make_float4(0.f, 0.f, 0.f, 0.f);
  if (half == 0) {
#pragma unroll
    for (int p = 0; p < 2; ++p) {
      const float* s = part + p * PL + row * 512 + tx * 4;
      float4 a = ld4(s), b = ld4(s + 256);
      v.x += a.x + b.x; v.y += a.y + b.y; v.z += a.z + b.z; v.w += a.w + b.w;
    }
  } else {
    const float* s = part + 2 * PL + row * 512 + tx * 4;
    float4 a = ld4(s), b = ld4(s + 256);
    v.x = a.x + b.x; v.y = a.y + b.y; v.z = a.z + b.z; v.w = a.w + b.w;
  }
  const float* bp = half ? b1 : b0;
  const float* sp = half ? s1 : s0;
  float4 b4 = ld4(bp + tx * 4);
  float4 s4 = ld4(sp + tx * 4);
  float4 o = rms_silu4(v.x + b4.x, v.y + b4.y, v.z + b4.z, v.w + b4.w, s4);
  st4(xb + row * 768 + half * 256 + tx * 4, o);
}

// ---------------- combine p=4 (obsfc0) + bias + rmsnorm(256) + silu ----------------
__global__ __launch_bounds__(256) void k_comb4(
    const float* __restrict__ part, const float* __restrict__ bias,
    const float* __restrict__ scale, float* __restrict__ dst) {
  const int tid = threadIdx.x, tx = tid & 63, wv = tid >> 6;
  const size_t row = blockIdx.x * 4 + wv;
  float4 v = make_float4(0.f, 0.f, 0.f, 0.f);
#pragma unroll
  for (int ks = 0; ks < 4; ++ks) {
    float4 t = ld4(part + (size_t)ks * 4096 * 256 + row * 256 + tx * 4);
    v.x += t.x; v.y += t.y; v.z += t.z; v.w += t.w;
  }
  float4 b4 = ld4(bias + tx * 4);
  float4 s4 = ld4(scale + tx * 4);
  float4 o = rms_silu4(v.x + b4.x, v.y + b4.y, v.z + b4.z, v.w + b4.w, s4);
  st4(dst + row * 256 + tx * 4, o);
}

// ---------------- hid0 block-linear via split-bf16 MFMA (validated round 6) ----------------
__global__ __launch_bounds__(512) void k_hid0m(
    const float* __restrict__ deter, const float* __restrict__ xb,
    const ushort* __restrict__ wsU,
    const float* __restrict__ hbias, float* __restrict__ yh) {
  __shared__ ushort Ah[64 * 32], Al[64 * 32];
  __shared__ ushort Wh[2][256 * 32], Wl[2][256 * 32];
  const int tid = threadIdx.x, lane = tid & 63, wv = tid >> 6;
  const int wr = wv >> 2, wc = wv & 3;
  const int g = blockIdx.x & 7;
  const int m0 = (int)(blockIdx.x >> 3) * 64;

  int wn0, wkb0, wn1, wkb1;
  dec_swz(tid * 16, wn0, wkb0);
  dec_swz(8192 + tid * 16, wn1, wkb1);
  const char* whhB = (const char*)(wsU + U_WHH) + (size_t)g * 256 * 2048;
  const char* whlB = (const char*)(wsU + U_WHL) + (size_t)g * 256 * 2048;

  const int arow = tid >> 2, akq = (tid & 3) * 8;
  const int abyte = swz_addr(arow, (tid & 3) * 16);
  float av[8];

  const f32x4 z4 = {0.f, 0.f, 0.f, 0.f};
  f32x4 acc[2][4];
#pragma unroll
  for (int i = 0; i < 2; ++i)
#pragma unroll
    for (int j = 0; j < 4; ++j) acc[i][j] = z4;

#define H_LOADA(kt) \
  if (tid < 256) { \
    int kg = (kt) * 32 + akq; \
    const float* p = (kg < 256) ? deter + (size_t)(m0 + arow) * 2048 + g * 256 + kg \
                                : xb + (size_t)(m0 + arow) * 768 + (kg - 256); \
    float4 u_ = ld4(p), w_ = ld4(p + 4); \
    av[0] = u_.x; av[1] = u_.y; av[2] = u_.z; av[3] = u_.w; \
    av[4] = w_.x; av[5] = w_.y; av[6] = w_.z; av[7] = w_.w; \
  }
#define H_WRITEA() \
  if (tid < 256) { \
    s16x8 h8, l8; \
    _Pragma("unroll") \
    for (int j = 0; j < 8; ++j) { \
      ushort h_ = f2bf(av[j]); \
      h8[j] = (short)h_; \
      l8[j] = (short)f2bf(av[j] - bf2f(h_)); \
    } \
    *(s16x8*)((char*)Ah + abyte) = h8; \
    *(s16x8*)((char*)Al + abyte) = l8; \
  }
#define H_ISSUEW(buf, kt) { \
    size_t o0_ = (size_t)wn0 * 2048 + (kt) * 64 + wkb0; \
    size_t o1_ = (size_t)wn1 * 2048 + (kt) * 64 + wkb1; \
    cp16g((char*)Wh[buf] + tid * 16, whhB + o0_); \
    cp16g((char*)Wh[buf] + 8192 + tid * 16, whhB + o1_); \
    cp16g((char*)Wl[buf] + tid * 16, whlB + o0_); \
    cp16g((char*)Wl[buf] + 8192 + tid * 16, whlB + o1_); \
  }

  H_LOADA(0);
  H_ISSUEW(0, 0);
  H_WRITEA();
  __syncthreads();
  int cur = 0;
  for (int t = 0; t < 32; ++t) {
    if (t < 31) { H_LOADA(t + 1); H_ISSUEW(cur ^ 1, t + 1); }
    const int k16 = (lane >> 4) * 16;
    s16x8 afh[2], afl[2];
#pragma unroll
    for (int mf = 0; mf < 2; ++mf) {
      int by = swz_addr(wr * 32 + mf * 16 + (lane & 15), k16);
      afh[mf] = *(const s16x8*)((const char*)Ah + by);
      afl[mf] = *(const s16x8*)((const char*)Al + by);
    }
#pragma unroll
    for (int nf = 0; nf < 4; ++nf) {
      int by = swz_addr(wc * 64 + nf * 16 + (lane & 15), k16);
      s16x8 bh = *(const s16x8*)((const char*)Wh[cur] + by);
      s16x8 bl = *(const s16x8*)((const char*)Wl[cur] + by);
#pragma unroll
      for (int mf = 0; mf < 2; ++mf) {
        acc[mf][nf] = mfma16(afh[mf], bh, acc[mf][nf]);
        acc[mf][nf] = mfma16(afh[mf], bl, acc[mf][nf]);
        acc[mf][nf] = mfma16(afl[mf], bh, acc[mf][nf]);
      }
    }
    __syncthreads();
    if (t < 31) H_WRITEA();
    __syncthreads();
    cur ^= 1;
  }
#undef H_LOADA
#undef H_WRITEA
#undef H_ISSUEW
#pragma unroll
  for (int mf = 0; mf < 2; ++mf) {
    int rbase = m0 + wr * 32 + mf * 16 + ((lane >> 4) << 2);
#pragma unroll
    for (int nf = 0; nf < 4; ++nf) {
      int col = wc * 64 + nf * 16 + (lane & 15);
      float b = hbias[g * 256 + col];
#pragma unroll
      for (int r = 0; r < 4; ++r)
        yh[(size_t)(rbase + r) * 2048 + g * 256 + col] = acc[mf][nf][r] + b;
    }
  }
}

// ---------------- in-place rmsnorm(2048)+silu ----------------
__global__ __launch_bounds__(256) void k_rmsnorm2048(
    float* __restrict__ xh, const float* __restrict__ scale) {
  const int b = blockIdx.x, tid = threadIdx.x;
  float* row = xh + (size_t)b * 2048;
  float4 v0 = ld4(row + tid * 8);
  float4 v1 = ld4(row + tid * 8 + 4);
  float ss = v0.x * v0.x + v0.y * v0.y + v0.z * v0.z + v0.w * v0.w +
             v1.x * v1.x + v1.y * v1.y + v1.z * v1.z + v1.w * v1.w;
#pragma unroll
  for (int off = 32; off; off >>= 1) ss += __shfl_xor(ss, off);
  __shared__ float wsum[4];
  if ((tid & 63) == 0) wsum[tid >> 6] = ss;
  __syncthreads();
  float tot = wsum[0] + wsum[1] + wsum[2] + wsum[3];
  float inv = 1.0f / sqrtf(tot * (1.0f / 2048.0f) + EPSN);
  float4 sc0 = ld4(scale + tid * 8);
  float4 sc1 = ld4(scale + tid * 8 + 4);
  float4 o0, o1;
  o0.x = siluf(v0.x * inv * sc0.x); o0.y = siluf(v0.y * inv * sc0.y);
  o0.z = siluf(v0.z * inv * sc0.z); o0.w = siluf(v0.w * inv * sc0.w);
  o1.x = siluf(v1.x * inv * sc1.x); o1.y = siluf(v1.y * inv * sc1.y);
  o1.z = siluf(v1.z * inv * sc1.z); o1.w = siluf(v1.w * inv * sc1.w);
  st4(row + tid * 8, o0);
  st4(row + tid * 8 + 4, o1);
}

// ---------------- gru block-linear via split-bf16 MFMA + fused GRU (validated round 6) ----------------
__global__ __launch_bounds__(512) void k_grum(
    const float* __restrict__ xh, const ushort* __restrict__ wsU,
    const float* __restrict__ gb, const float* __restrict__ deter,
    float* __restrict__ newdet) {
  __shared__ ushort Ah[128 * 32], Al[128 * 32];
  __shared__ ushort Wh[2][192 * 32], Wl[2][192 * 32];
  const int tid = threadIdx.x, lane = tid & 63, wv = tid >> 6;
  const int wr = wv >> 2, wc = wv & 3;
  const int g = blockIdx.x & 7;
  const int nc = (int)(blockIdx.x >> 3) & 3;
  const int m0 = (int)(blockIdx.x >> 5) * 128;

  int wn0, wkb0, wn1, wkb1;
  dec_swz(tid * 16, wn0, wkb0);
  dec_swz(8192 + tid * 16, wn1, wkb1);
  const char* wghB = (const char*)(wsU + U_WGH);
  const char* wglB = (const char*)(wsU + U_WGL);
  const size_t wo0 = (size_t)(g * 768 + ((wn0 >> 6) << 8) + nc * 64 + (wn0 & 63)) * 512 + wkb0;
  const size_t wo1 = (size_t)(g * 768 + ((wn1 >> 6) << 8) + nc * 64 + (wn1 & 63)) * 512 + wkb1;

  const int arow = tid >> 2, akq = (tid & 3) * 8;
  const int abyte = swz_addr(arow, (tid & 3) * 16);
  float av[8];

  const f32x4 z4 = {0.f, 0.f, 0.f, 0.f};
  f32x4 acc[4][3];
#pragma unroll
  for (int i = 0; i < 4; ++i)
#pragma unroll
    for (int j = 0; j < 3; ++j) acc[i][j] = z4;

#define G_LOADA(kt) { \
    const float* p = xh + (size_t)(m0 + arow) * 2048 + g * 256 + (kt) * 32 + akq; \
    float4 u_ = ld4(p), w_ = ld4(p + 4); \
    av[0] = u_.x; av[1] = u_.y; av[2] = u_.z; av[3] = u_.w; \
    av[4] = w_.x; av[5] = w_.y; av[6] = w_.z; av[7] = w_.w; \
  }
#define G_WRITEA() { \
    s16x8 h8, l8; \
    _Pragma("unroll") \
    for (int j = 0; j < 8; ++j) { \
      ushort h_ = f2bf(av[j]); \
      h8[j] = (short)h_; \
      l8[j] = (short)f2bf(av[j] - bf2f(h_)); \
    } \
    *(s16x8*)((char*)Ah + abyte) = h8; \
    *(s16x8*)((char*)Al + abyte) = l8; \
  }
#define G_ISSUEW(buf, kt) { \
    cp16g((char*)Wh[buf] + tid * 16, wghB + wo0 + (kt) * 64); \
    cp16g((char*)Wl[buf] + tid * 16, wglB + wo0 + (kt) * 64); \
    if (tid < 256) { \
      cp16g((char*)Wh[buf] + 8192 + tid * 16, wghB + wo1 + (kt) * 64); \
      cp16g((char*)Wl[buf] + 8192 + tid * 16, wglB + wo1 + (kt) * 64); \
    } }

  G_LOADA(0);
  G_ISSUEW(0, 0);
  G_WRITEA();
  __syncthreads();
  int cur = 0;
  for (int t = 0; t < 8; ++t) {
    if (t < 7) { G_LOADA(t + 1); G_ISSUEW(cur ^ 1, t + 1); }
    const int k16 = (lane >> 4) * 16;
    s16x8 afh[4], afl[4];
#pragma unroll
    for (int mf = 0; mf < 4; ++mf) {
      int by = swz_addr(wr * 64 + mf * 16 + (lane & 15), k16);
      afh[mf] = *(const s16x8*)((const char*)Ah + by);
      afl[mf] = *(const s16x8*)((const char*)Al + by);
    }
#pragma unroll
    for (int gt = 0; gt < 3; ++gt) {
      int by = swz_addr(gt * 64 + wc * 16 + (lane & 15), k16);
      s16x8 bh = *(const s16x8*)((const char*)Wh[cur] + by);
      s16x8 bl = *(const s16x8*)((const char*)Wl[cur] + by);
#pragma unroll
      for (int mf = 0; mf < 4; ++mf) {
        acc[mf][gt] = mfma16(afh[mf], bh, acc[mf][gt]);
        acc[mf][gt] = mfma16(afh[mf], bl, acc[mf][gt]);
        acc[mf][gt] = mfma16(afl[mf], bh, acc[mf][gt]);
      }
    }
    __syncthreads();
    if (t < 7) G_WRITEA();
    __syncthreads();
    cur ^= 1;
  }
#undef G_LOADA
#undef G_WRITEA
#undef G_ISSUEW
  const int col = nc * 64 + wc * 16 + (lane & 15);
  const float br = gb[g * 768 + col];
  const float bc = gb[g * 768 + 256 + col];
  const float bu = gb[g * 768 + 512 + col];
#pragma unroll
  for (int mf = 0; mf < 4; ++mf) {
    int rbase = m0 + wr * 64 + mf * 16 + ((lane >> 4) << 2);
#pragma unroll
    for (int r = 0; r < 4; ++r) {
      int row = rbase + r;
      float rr = sigm(acc[mf][0][r] + br);
      float cc = acc[mf][1][r] + bc;
      float uu = sigm(acc[mf][2][r] + bu - 1.0f);
      float d = deter[(size_t)row * 2048 + g * 256 + col];
      newdet[(size_t)row * 2048 + g * 256 + col] =
          uu * tanhf(rr * cc) + (1.0f - uu) * d;
    }
  }
}

// ---------------- obs_out via split-bf16 MFMA -> logit (+bias) ----------------
__global__ __launch_bounds__(512) void k_obsoutm(
    const float* __restrict__ hb, const ushort* __restrict__ wsU,
    const float* __restrict__ ob, float* __restrict__ logit) {
  __shared__ ushort Ah[64 * 32], Al[64 * 32];
  __shared__ ushort Wh[2][256 * 32], Wl[2][256 * 32];
  const int tid = threadIdx.x, lane = tid & 63, wv = tid >> 6;
  const int wr = wv >> 2, wc = wv & 3;
  const int half = blockIdx.x & 1;
  const int m0 = (int)(blockIdx.x >> 1) * 64;

  int wn0, wkb0, wn1, wkb1;
  dec_swz(tid * 16, wn0, wkb0);
  dec_swz(8192 + tid * 16, wn1, wkb1);
  const char* whB = (const char*)(wsU + U_WOH) + (size_t)half * 256 * 512;
  const char* wlB = (const char*)(wsU + U_WOL) + (size_t)half * 256 * 512;
  const size_t wo0 = (size_t)wn0 * 512 + wkb0;
  const size_t wo1 = (size_t)wn1 * 512 + wkb1;

  const int arow = tid >> 2, akq = (tid & 3) * 8;
  const int abyte = swz_addr(arow, (tid & 3) * 16);
  float av[8];

  const f32x4 z4 = {0.f, 0.f, 0.f, 0.f};
  f32x4 acc[2][4];
#pragma unroll
  for (int i = 0; i < 2; ++i)
#pragma unroll
    for (int j = 0; j < 4; ++j) acc[i][j] = z4;

#define O_LOADA(kt) \
  if (tid < 256) { \
    const float* p = hb + (size_t)(m0 + arow) * 256 + (kt) * 32 + akq; \
    float4 u_ = ld4(p), w_ = ld4(p + 4); \
    av[0] = u_.x; av[1] = u_.y; av[2] = u_.z; av[3] = u_.w; \
    av[4] = w_.x; av[5] = w_.y; av[6] = w_.z; av[7] = w_.w; \
  }
#define O_WRITEA() \
  if (tid < 256) { \
    s16x8 h8, l8; \
    _Pragma("unroll") \
    for (int j = 0; j < 8; ++j) { \
      ushort h_ = f2bf(av[j]); \
      h8[j] = (short)h_; \
      l8[j] = (short)f2bf(av[j] - bf2f(h_)); \
    } \
    *(s16x8*)((char*)Ah + abyte) = h8; \
    *(s16x8*)((char*)Al + abyte) = l8; \
  }
#define O_ISSUEW(buf, kt) { \
    cp16g((char*)Wh[buf] + tid * 16, whB + wo0 + (kt) * 64); \
    cp16g((char*)Wh[buf] + 8192 + tid * 16, whB + wo1 + (kt) * 64); \
    cp16g((char*)Wl[buf] + tid * 16, wlB + wo0 + (kt) * 64); \
    cp16g((char*)Wl[buf] + 8192 + tid * 16, wlB + wo1 + (kt) * 64); \
  }

  O_LOADA(0);
  O_ISSUEW(0, 0);
  O_WRITEA();
  __syncthreads();
  int cur = 0;
  for (int t = 0; t < 8; ++t) {
    if (t < 7) { O_LOADA(t + 1); O_ISSUEW(cur ^ 1, t + 1); }
    const int k16 = (lane >> 4) * 16;
    s16x8 afh[2], afl[2];
#pragma unroll
    for (int mf = 0; mf < 2; ++mf) {
      int by = swz_addr(wr * 32 + mf * 16 + (lane & 15), k16);
      afh[mf] = *(const s16x8*)((const char*)Ah + by);
      afl[mf] = *(const s16x8*)((const char*)Al + by);
    }
#pragma unroll
    for (int nf = 0; nf < 4; ++nf) {
      int by = swz_addr(wc * 64 + nf * 16 + (lane & 15), k16);
      s16x8 bh = *(const s16x8*)((const char*)Wh[cur] + by);
      s16x8 bl = *(const s16x8*)((const char*)Wl[cur] + by);
#pragma unroll
      for (int mf = 0; mf < 2; ++mf) {
        acc[mf][nf] = mfma16(afh[mf], bh, acc[mf][nf]);
        acc[mf][nf] = mfma16(afh[mf], bl, acc[mf][nf]);
        acc[mf][nf] = mfma16(afl[mf], bh, acc[mf][nf]);
      }
    }
    __syncthreads();
    if (t < 7) O_WRITEA();
    __syncthreads();
    cur ^= 1;
  }
#undef O_LOADA
#undef O_WRITEA
#undef O_ISSUEW
#pragma unroll
  for (int mf = 0; mf < 2; ++mf) {
    int rbase = m0 + wr * 32 + mf * 16 + ((lane >> 4) << 2);
#pragma unroll
    for (int nf = 0; nf < 4; ++nf) {
      int col = half * 256 + wc * 64 + nf * 16 + (lane & 15);
      float b = ob[col];
#pragma unroll
      for (int r = 0; r < 4; ++r)
        logit[(size_t)(rbase + r) * 512 + col] = acc[mf][nf][r] + b;
    }
  }
}

// ---------------- argmax -> one-hot (first-index ties) ----------------
__global__ __launch_bounds__(256) void k_argmax(
    const float* __restrict__ logit, float* __restrict__ stoch_out) {
  const size_t row = blockIdx.x * 4 + (threadIdx.x >> 6);
  const int lane = threadIdx.x & 63;
  const float* lp = logit + row * 512 + lane * 8;
  float4 a = ld4(lp), b = ld4(lp + 4);
  float v[8] = {a.x, a.y, a.z, a.w, b.x, b.y, b.z, b.w};
  float bv = v[0]; int bi = 0;
#pragma unroll
  for (int j = 1; j < 8; ++j)
    if (v[j] > bv) { bv = v[j]; bi = j; }
  bi += lane * 8;
  float pv = __shfl_xor(bv, 1);
  int   pi = __shfl_xor(bi, 1);
  if (pv > bv || (pv == bv && pi < bi)) { bv = pv; bi = pi; }
  float4 o0, o1;
  int base = lane * 8;
  o0.x = (bi == base + 0) ? 1.f : 0.f;
  o0.y = (bi == base + 1) ? 1.f : 0.f;
  o0.z = (bi == base + 2) ? 1.f : 0.f;
  o0.w = (bi == base + 3) ? 1.f : 0.f;
  o1.x = (bi == base + 4) ? 1.f : 0.f;
  o1.y = (bi == base + 5) ? 1.f : 0.f;
  o1.z = (bi == base + 6) ? 1.f : 0.f;
  o1.w = (bi == base + 7) ? 1.f : 0.f;
  st4(stoch_out + row * 512 + base, o0);
  st4(stoch_out + row * 512 + base + 4, o1);
}

// ---------------- launcher ----------------
extern "C" void kernel_launch(void* const* d_in, const int* in_sizes, int n_in,
                              void* d_out, int out_size, void* d_ws, size_t ws_size,
                              hipStream_t stream) {
  (void)in_sizes; (void)n_in; (void)out_size; (void)ws_size;
  const float* stoch      = (const float*)d_in[0];
  const float* deter      = (const float*)d_in[1];
  const float* action     = (const float*)d_in[2];
  const float* embed      = (const float*)d_in[3];
  const float* in0_w      = (const float*)d_in[4];
  const float* in0_b      = (const float*)d_in[5];
  const float* n0_s       = (const float*)d_in[6];
  const float* in1_w      = (const float*)d_in[7];
  const float* in1_b      = (const float*)d_in[8];
  const float* n1_s       = (const float*)d_in[9];
  const float* in2_w      = (const float*)d_in[10];
  const float* in2_b      = (const float*)d_in[11];
  const float* n2_s       = (const float*)d_in[12];
  const float* hid0_k     = (const float*)d_in[13];
  const float* hid0_b     = (const float*)d_in[14];
  const float* hidn_s     = (const float*)d_in[15];
  const float* gru_k      = (const float*)d_in[16];
  const float* gru_b      = (const float*)d_in[17];
  const float* obs_fc0_w  = (const float*)d_in[18];
  const float* obs_fc0_b  = (const float*)d_in[19];
  const float* obs_n_s    = (const float*)d_in[20];
  const float* obs_out_w  = (const float*)d_in[21];
  const float* obs_out_b  = (const float*)d_in[22];

  float*  out = (float*)d_out;
  float*  ws  = (float*)d_ws;
  ushort* wsU = (ushort*)d_ws;
  float*  xb  = ws + F_XB;
  float*  xh  = ws + F_XH;   // also split-K partial area (dead at both uses)
  float*  hb  = ws + F_HB;   // inside xh, after mode-1 partials
  float*  part = xh;

  hipLaunchKernelGGL(k_prep, dim3(2176), dim3(256), 0, stream,
                     hid0_k, gru_k, in0_w, in1_w, obs_fc0_w, obs_out_w, wsU);
  hipLaunchKernelGGL(k_x2, dim3(32), dim3(512), 0, stream,
                     action, in2_w, in2_b, n2_s, xb);
  hipLaunchKernelGGL(k_gemm256, dim3(384), dim3(512), 0, stream,
                     0, deter, stoch, out + OFF_DETER, embed, wsU, part);
  hipLaunchKernelGGL(k_comb_in, dim3(2048), dim3(256), 0, stream,
                     part, in0_b, n0_s, in1_b, n1_s, xb);
  hipLaunchKernelGGL(k_hid0m, dim3(512), dim3(512), 0, stream,
                     deter, xb, wsU, hid0_b, xh);
  hipLaunchKernelGGL(k_rmsnorm2048, dim3(4096), dim3(256), 0, stream, xh, hidn_s);
  hipLaunchKernelGGL(k_grum, dim3(1024), dim3(512), 0, stream,
                     xh, wsU, gru_b, deter, out + OFF_DETER);
  hipLaunchKernelGGL(k_gemm256, dim3(256), dim3(512), 0, stream,
                     1, deter, stoch, out + OFF_DETER, embed, wsU, part);
  hipLaunchKernelGGL(k_comb4, dim3(1024), dim3(256), 0, stream,
                     part, obs_fc0_b, obs_n_s, hb);
  hipLaunchKernelGGL(k_obsoutm, dim3(128), dim3(512), 0, stream,
                     hb, wsU, obs_out_b, out + OFF_LOGIT);
  hipLaunchKernelGGL(k_argmax, dim3(1024), dim3(256), 0, stream,
                     out + OFF_LOGIT, out + OFF_STOCH);
}

// Round 10
// 241.229 us; speedup vs baseline: 29.3192x; 1.1218x over previous
//
#include <hip/hip_runtime.h>
#include <cmath>

// ---------------- problem constants ----------------
constexpr int BATCH = 4096;
constexpr float EPSN = 1e-4f;

// d_out layout (floats): [new_stoch | new_deter | logit]
constexpr int OFF_STOCH = 0;
constexpr int OFF_DETER = BATCH * 512;
constexpr int OFF_LOGIT = OFF_DETER + BATCH * 2048;

typedef unsigned short ushort;
typedef __attribute__((ext_vector_type(4))) float f32x4;
typedef __attribute__((ext_vector_type(8))) short s16x8;
struct us4 { ushort x, y, z, w; };

// ---------------- ws layout (PROVEN 61.5 MiB budget — do not exceed) ----------------
constexpr size_t U_WHH = 0;                      // hid hi  [g][256][1024]
constexpr size_t U_WHL = U_WHH + 2097152;
constexpr size_t U_WGH = U_WHL + 2097152;        // gru hi  [g][768][256]
constexpr size_t U_WGL = U_WGH + 1572864;
constexpr size_t U_WFH = U_WGL + 1572864;        // obs_fc0 hi [256][3072]
constexpr size_t U_WFL = U_WFH + 786432;
constexpr size_t U_WOH = U_WFL + 786432;         // obs_out hi [512][256]
constexpr size_t U_WOL = U_WOH + 131072;
constexpr size_t U_PEND = U_WOL + 131072;        // 9,175,040 ushorts
constexpr size_t F_XB = U_PEND / 2;              // xb: packed [4096][768h|768l] bf16 (12.6MB)
constexpr size_t F_XH = F_XB + 3145728;          // xh: f32 yh then packed [2048h|2048l]/row
// total = F_XH + 8,388,608 f32 = 61.5 MiB
constexpr size_t U_X0H = (F_XH + 6291456) * 2;   // transient in0_w planes in xh tail
constexpr size_t U_X0L = U_X0H + 524288;
constexpr size_t U_X1H = U_X0L + 524288;
constexpr size_t U_X1L = U_X1H + 131072;
constexpr size_t F_HB = F_XH + 4194304;          // hb packed [4096][256h|256l], after mode-1 partials

#define DINLINE __device__ __forceinline__

DINLINE float sigm(float x)  { return 1.0f / (1.0f + expf(-x)); }
DINLINE float siluf(float x) { return x / (1.0f + expf(-x)); }

DINLINE float4 ld4(const float* p) { return *reinterpret_cast<const float4*>(p); }
DINLINE void st4(float* p, float4 v) { *reinterpret_cast<float4*>(p) = v; }

DINLINE ushort f2bf(float x) {  // RNE f32->bf16 bits
  unsigned u = __float_as_uint(x);
  unsigned r = u + 0x7fffu + ((u >> 16) & 1u);
  return (ushort)(r >> 16);
}
DINLINE float bf2f(ushort h) { return __uint_as_float(((unsigned)h) << 16); }

DINLINE void cp16g(void* lds, const void* g) {
  __builtin_amdgcn_global_load_lds(
      (const __attribute__((address_space(1))) unsigned int*)g,
      (__attribute__((address_space(3))) unsigned int*)lds, 16, 0, 0);
}

DINLINE f32x4 mfma16(s16x8 a, s16x8 b, f32x4 c) {
  return __builtin_amdgcn_mfma_f32_16x16x32_bf16(a, b, c, 0, 0, 0);
}

// XOR-swizzled LDS byte address for [row][64B of k] bf16 tiles (validated round 6).
DINLINE int swz_addr(int row, int kb0) {
  return (row * 64 + kb0) ^ ((row & 7) << 4);
}
DINLINE void dec_swz(int D, int& row, int& kb) {
  int r2 = (D >> 8) & 1;
  int r0 = ((D >> 6) & 1) ^ r2;
  row = ((D >> 7) << 1) | r0;
  kb = (D & 48) ^ ((row & 3) << 4);
}

// split helper: f32 -> (hi, lo) bf16
DINLINE void split2(float x, ushort& h, ushort& l) {
  h = f2bf(x);
  l = f2bf(x - bf2f(h));
}

// rmsnorm(256)+silu: lane holds 4 values of one row.
DINLINE float4 rms_silu4(float v0, float v1, float v2, float v3, float4 s4) {
  float ss = v0 * v0 + v1 * v1 + v2 * v2 + v3 * v3;
#pragma unroll
  for (int off = 32; off; off >>= 1) ss += __shfl_xor(ss, off);
  float inv = 1.0f / sqrtf(ss * (1.0f / 256.0f) + EPSN);
  float4 o;
  o.x = siluf(v0 * inv * s4.x); o.y = siluf(v1 * inv * s4.y);
  o.z = siluf(v2 * inv * s4.z); o.w = siluf(v3 * inv * s4.w);
  return o;
}

// ---------------- kernel 1: weight prep (unchanged, validated) ----------------
__global__ __launch_bounds__(256) void k_prep(
    const float* __restrict__ hk, const float* __restrict__ gk,
    const float* __restrict__ w0, const float* __restrict__ w1,
    const float* __restrict__ wf, const float* __restrict__ wo,
    ushort* __restrict__ wsU) {
  __shared__ float L[64 * 65];
  const int bid = blockIdx.x, tid = threadIdx.x;
  if (bid < 1792) {
    int t = bid * 256 + tid;
    const float* src; ushort* dh; ushort* dl; int e, plane;
    if (t < 262144) { e = t; src = hk + (size_t)e * 8; dh = wsU + U_WHH; dl = wsU + U_WHL; plane = 262144; }
    else { e = t - 262144; src = gk + (size_t)e * 8; dh = wsU + U_WGH; dl = wsU + U_WGL; plane = 196608; }
    float4 v0 = ld4(src), v1 = ld4(src + 4);
    float vv[8] = {v0.x, v0.y, v0.z, v0.w, v1.x, v1.y, v1.z, v1.w};
#pragma unroll
    for (int g2 = 0; g2 < 8; ++g2) {
      ushort h, l; split2(vv[g2], h, l);
      dh[(size_t)g2 * plane + e] = h;
      dl[(size_t)g2 * plane + e] = l;
    }
    return;
  }
  int t = bid - 1792;
  const float* src; ushort* dh; ushort* dl; int K, N;
  if (t < 128)      { src = w0; dh = wsU + U_X0H; dl = wsU + U_X0L; K = 2048; N = 256; }
  else if (t < 160) { t -= 128; src = w1; dh = wsU + U_X1H; dl = wsU + U_X1L; K = 512;  N = 256; }
  else if (t < 352) { t -= 160; src = wf; dh = wsU + U_WFH; dl = wsU + U_WFL; K = 3072; N = 256; }
  else              { t -= 352; src = wo; dh = wsU + U_WOH; dl = wsU + U_WOL; K = 256;  N = 512; }
  const int ntiles = N / 64;
  const int k0 = (t / ntiles) * 64, n0 = (t % ntiles) * 64;
#pragma unroll
  for (int q = 0; q < 4; ++q) {
    int row = q * 16 + (tid >> 4), col = (tid & 15) * 4;
    float4 v = ld4(src + (size_t)(k0 + row) * N + n0 + col);
    L[row * 65 + col]     = v.x;
    L[row * 65 + col + 1] = v.y;
    L[row * 65 + col + 2] = v.z;
    L[row * 65 + col + 3] = v.w;
  }
  __syncthreads();
  const int n = tid >> 2, kc = (tid & 3) * 16;
  s16x8 h0, h1, l0v, l1v;
#pragma unroll
  for (int j = 0; j < 16; ++j) {
    ushort h, l; split2(L[(kc + j) * 65 + n], h, l);
    if (j < 8) { h0[j] = (short)h; l0v[j] = (short)l; }
    else       { h1[j - 8] = (short)h; l1v[j - 8] = (short)l; }
  }
  size_t ob = (size_t)(n0 + n) * K + k0 + kc;
  *(s16x8*)(dh + ob)     = h0;
  *(s16x8*)(dh + ob + 8) = h1;
  *(s16x8*)(dl + ob)     = l0v;
  *(s16x8*)(dl + ob + 8) = l1v;
}

// ---------------- unified split-bf16 MFMA GEMM (single barrier/tile, A dbuf) ----------------
__global__ __launch_bounds__(512) void k_gemm256(
    int mode,
    const float* __restrict__ deter, const float* __restrict__ stoch,
    const float* __restrict__ newdet, const float* __restrict__ embed,
    const ushort* __restrict__ wsU, float* __restrict__ part) {
  __shared__ ushort Ah[2][64 * 32], Al[2][64 * 32];
  __shared__ ushort Wh[2][256 * 32], Wl[2][256 * 32];
  const int tid = threadIdx.x, lane = tid & 63, wv = tid >> 6;
  const int wr = wv >> 2, wc = wv & 3;
  const int bid = blockIdx.x;
  constexpr size_t PL0 = (size_t)4096 * 512;

  const float* A0; const float* A1 = nullptr;
  int lda0, lda1 = 0, ksw = 1 << 30;
  const ushort* whp; const ushort* wlp;
  int KwB, kbase, KT, m0, dstride, dcol;
  float* dst;

  if (mode == 0) {
    if (bid < 256) {
      int ks = bid & 3; m0 = (bid >> 2) * 64; kbase = ks * 512; KT = 16;
      A0 = deter; lda0 = 2048;
      whp = wsU + U_X0H; wlp = wsU + U_X0L; KwB = 4096;
      dst = part + (size_t)(ks >> 1) * PL0; dstride = 512; dcol = (ks & 1) * 256;
    } else {
      int b = bid - 256; int ks = b & 1; m0 = (b >> 1) * 64; kbase = ks * 256; KT = 8;
      A0 = stoch; lda0 = 512;
      whp = wsU + U_X1H; wlp = wsU + U_X1L; KwB = 1024;
      dst = part + 2 * PL0; dstride = 512; dcol = ks * 256;
    }
  } else {
    int ks = bid & 3; m0 = (bid >> 2) * 64; kbase = ks * 768; KT = 24;
    A0 = newdet; lda0 = 2048; A1 = embed; lda1 = 1024; ksw = 2048;
    whp = wsU + U_WFH; wlp = wsU + U_WFL; KwB = 6144;
    dst = part + (size_t)ks * 4096 * 256; dstride = 256; dcol = 0;
  }

  int wn0, wkb0, wn1, wkb1;
  dec_swz(tid * 16, wn0, wkb0);
  dec_swz(8192 + tid * 16, wn1, wkb1);
  const char* whB = (const char*)whp;
  const char* wlB = (const char*)wlp;
  const size_t wo0 = (size_t)wn0 * KwB + kbase * 2 + wkb0;
  const size_t wo1 = (size_t)wn1 * KwB + kbase * 2 + wkb1;

  const int arow = tid >> 2, akq = (tid & 3) * 8;
  const int abyte = swz_addr(arow, (tid & 3) * 16);
  float av[8];

  const f32x4 z4 = {0.f, 0.f, 0.f, 0.f};
  f32x4 acc[2][4];
#pragma unroll
  for (int i = 0; i < 2; ++i)
#pragma unroll
    for (int j = 0; j < 4; ++j) acc[i][j] = z4;

#define U_LOADA(kt) \
  if (tid < 256) { \
    int kg = kbase + (kt) * 32 + akq; \
    const float* p = (kg < ksw) ? A0 + (size_t)(m0 + arow) * lda0 + kg \
                                : A1 + (size_t)(m0 + arow) * lda1 + (kg - ksw); \
    float4 u_ = ld4(p), w_ = ld4(p + 4); \
    av[0] = u_.x; av[1] = u_.y; av[2] = u_.z; av[3] = u_.w; \
    av[4] = w_.x; av[5] = w_.y; av[6] = w_.z; av[7] = w_.w; \
  }
#define U_WRITEA(buf) \
  if (tid < 256) { \
    s16x8 h8, l8; \
    _Pragma("unroll") \
    for (int j = 0; j < 8; ++j) { \
      ushort h_, l_; split2(av[j], h_, l_); \
      h8[j] = (short)h_; l8[j] = (short)l_; \
    } \
    *(s16x8*)((char*)Ah[buf] + abyte) = h8; \
    *(s16x8*)((char*)Al[buf] + abyte) = l8; \
  }
#define U_ISSUEW(buf, kt) { \
    cp16g((char*)Wh[buf] + tid * 16, whB + wo0 + (kt) * 64); \
    cp16g((char*)Wh[buf] + 8192 + tid * 16, whB + wo1 + (kt) * 64); \
    cp16g((char*)Wl[buf] + tid * 16, wlB + wo0 + (kt) * 64); \
    cp16g((char*)Wl[buf] + 8192 + tid * 16, wlB + wo1 + (kt) * 64); \
  }

  U_LOADA(0);
  U_ISSUEW(0, 0);
  U_WRITEA(0);
  __syncthreads();
  int cur = 0;
  for (int t = 0; t < KT; ++t) {
    if (t + 1 < KT) { U_ISSUEW(cur ^ 1, t + 1); U_LOADA(t + 1); }
    const int k16 = (lane >> 4) * 16;
    s16x8 afh[2], afl[2];
#pragma unroll
    for (int mf = 0; mf < 2; ++mf) {
      int by = swz_addr(wr * 32 + mf * 16 + (lane & 15), k16);
      afh[mf] = *(const s16x8*)((const char*)Ah[cur] + by);
      afl[mf] = *(const s16x8*)((const char*)Al[cur] + by);
    }
#pragma unroll
    for (int nf = 0; nf < 4; ++nf) {
      int by = swz_addr(wc * 64 + nf * 16 + (lane & 15), k16);
      s16x8 bh = *(const s16x8*)((const char*)Wh[cur] + by);
      s16x8 bl = *(const s16x8*)((const char*)Wl[cur] + by);
#pragma unroll
      for (int mf = 0; mf < 2; ++mf) {
        acc[mf][nf] = mfma16(afh[mf], bh, acc[mf][nf]);
        acc[mf][nf] = mfma16(afh[mf], bl, acc[mf][nf]);
        acc[mf][nf] = mfma16(afl[mf], bh, acc[mf][nf]);
      }
    }
    if (t + 1 < KT) { U_WRITEA(cur ^ 1); }
    __syncthreads();
    cur ^= 1;
  }
#undef U_LOADA
#undef U_WRITEA
#undef U_ISSUEW
#pragma unroll
  for (int mf = 0; mf < 2; ++mf) {
    int rbase = m0 + wr * 32 + mf * 16 + ((lane >> 4) << 2);
#pragma unroll
    for (int nf = 0; nf < 4; ++nf) {
      int col = dcol + wc * 64 + nf * 16 + (lane & 15);
#pragma unroll
      for (int r = 0; r < 4; ++r)
        dst[(size_t)(rbase + r) * dstride + col] = acc[mf][nf][r];
    }
  }
}

// ---------------- x2: action (K=17) f32 projection + rmsnorm + silu -> packed xb ----------------
__global__ __launch_bounds__(512) void k_x2(
    const float* __restrict__ action, const float* __restrict__ w2,
    const float* __restrict__ b2, const float* __restrict__ s2,
    ushort* __restrict__ xbp) {
  __shared__ float W2s[17 * 256];
  __shared__ float A2s[128 * 20];
  const int tid = threadIdx.x, tx = tid & 63, wv = tid >> 6;
  const int m0 = blockIdx.x * 128;
  for (int e = tid; e < 17 * 256; e += 512) W2s[e] = w2[e];
  for (int e = tid; e < 128 * 17; e += 512) {
    int r = e / 17, c = e % 17;
    float a = action[(size_t)(m0 + r) * 17 + c];
    float m = fabsf(a);
    A2s[r * 20 + c] = a / (m > 1.f ? m : 1.f);
  }
  __syncthreads();
  float4 acc2[16];
#pragma unroll
  for (int r = 0; r < 16; ++r) acc2[r] = make_float4(0.f, 0.f, 0.f, 0.f);
#pragma unroll
  for (int k = 0; k < 17; ++k) {
    float4 w4 = ld4(W2s + k * 256 + tx * 4);
#pragma unroll
    for (int r = 0; r < 16; ++r) {
      float av = A2s[(wv * 16 + r) * 20 + k];
      acc2[r].x = fmaf(av, w4.x, acc2[r].x);
      acc2[r].y = fmaf(av, w4.y, acc2[r].y);
      acc2[r].z = fmaf(av, w4.z, acc2[r].z);
      acc2[r].w = fmaf(av, w4.w, acc2[r].w);
    }
  }
  float4 b4 = ld4(b2 + tx * 4);
  float4 s4 = ld4(s2 + tx * 4);
#pragma unroll
  for (int r = 0; r < 16; ++r) {
    float4 o = rms_silu4(acc2[r].x + b4.x, acc2[r].y + b4.y,
                         acc2[r].z + b4.z, acc2[r].w + b4.w, s4);
    us4 h4, l4;
    split2(o.x, h4.x, l4.x); split2(o.y, h4.y, l4.y);
    split2(o.z, h4.z, l4.z); split2(o.w, h4.w, l4.w);
    size_t rb = (size_t)(m0 + wv * 16 + r) * 1536;
    *(us4*)(xbp + rb + 512 + tx * 4) = h4;
    *(us4*)(xbp + rb + 768 + 512 + tx * 4) = l4;
  }
}

// ---------------- combine: x0 | x1 + bias + rmsnorm + silu -> packed xb ----------------
__global__ __launch_bounds__(256) void k_comb_in(
    const float* __restrict__ part,
    const float* __restrict__ b0, const float* __restrict__ s0,
    const float* __restrict__ b1, const float* __restrict__ s1,
    ushort* __restrict__ xbp) {
  const int tid = threadIdx.x, tx = tid & 63, wv = tid >> 6;
  const size_t row = blockIdx.x * 2 + (wv >> 1);
  const int half = wv & 1;
  constexpr size_t PL = (size_t)4096 * 512;
  float4 v = make_float4(0.f, 0.f, 0.f, 0.f);
  if (half == 0) {
#pragma unroll
    for (int p = 0; p < 2; ++p) {
      const float* s = part + p * PL + row * 512 + tx * 4;
      float4 a = ld4(s), b = ld4(s + 256);
      v.x += a.x + b.x; v.y += a.y + b.y; v.z += a.z + b.z; v.w += a.w + b.w;
    }
  } else {
    const float* s = part + 2 * PL + row * 512 + tx * 4;
    float4 a = ld4(s), b = ld4(s + 256);
    v.x = a.x + b.x; v.y = a.y + b.y; v.z = a.z + b.z; v.w = a.w + b.w;
  }
  const float* bp = half ? b1 : b0;
  const float* sp = half ? s1 : s0;
  float4 b4 = ld4(bp + tx * 4);
  float4 s4 = ld4(sp + tx * 4);
  float4 o = rms_silu4(v.x + b4.x, v.y + b4.y, v.z + b4.z, v.w + b4.w, s4);
  us4 h4, l4;
  split2(o.x, h4.x, l4.x); split2(o.y, h4.y, l4.y);
  split2(o.z, h4.z, l4.z); split2(o.w, h4.w, l4.w);
  *(us4*)(xbp + row * 1536 + half * 256 + tx * 4) = h4;
  *(us4*)(xbp + row * 1536 + 768 + half * 256 + tx * 4) = l4;
}

// ---------------- combine p=4 (obsfc0) -> packed hb ----------------
__global__ __launch_bounds__(256) void k_comb4(
    const float* __restrict__ part, const float* __restrict__ bias,
    const float* __restrict__ scale, ushort* __restrict__ hbp) {
  const int tid = threadIdx.x, tx = tid & 63, wv = tid >> 6;
  const size_t row = blockIdx.x * 4 + wv;
  float4 v = make_float4(0.f, 0.f, 0.f, 0.f);
#pragma unroll
  for (int ks = 0; ks < 4; ++ks) {
    float4 t = ld4(part + (size_t)ks * 4096 * 256 + row * 256 + tx * 4);
    v.x += t.x; v.y += t.y; v.z += t.z; v.w += t.w;
  }
  float4 b4 = ld4(bias + tx * 4);
  float4 s4 = ld4(scale + tx * 4);
  float4 o = rms_silu4(v.x + b4.x, v.y + b4.y, v.z + b4.z, v.w + b4.w, s4);
  us4 h4, l4;
  split2(o.x, h4.x, l4.x); split2(o.y, h4.y, l4.y);
  split2(o.z, h4.z, l4.z); split2(o.w, h4.w, l4.w);
  *(us4*)(hbp + row * 512 + tx * 4) = h4;
  *(us4*)(hbp + row * 512 + 256 + tx * 4) = l4;
}

// ---------------- hid0: deter tiles (t<8) reg-split, xb tiles (t>=8) cp16 ----------------
__global__ __launch_bounds__(512) void k_hid0m(
    const float* __restrict__ deter, const ushort* __restrict__ xbp,
    const ushort* __restrict__ wsU,
    const float* __restrict__ hbias, float* __restrict__ yh) {
  __shared__ ushort Ah[2][64 * 32], Al[2][64 * 32];
  __shared__ ushort Wh[2][256 * 32], Wl[2][256 * 32];
  const int tid = threadIdx.x, lane = tid & 63, wv = tid >> 6;
  const int wr = wv >> 2, wc = wv & 3;
  const int g = blockIdx.x & 7;
  const int m0 = (int)(blockIdx.x >> 3) * 64;

  int wn0, wkb0, wn1, wkb1;
  dec_swz(tid * 16, wn0, wkb0);
  dec_swz(8192 + tid * 16, wn1, wkb1);
  const char* whhB = (const char*)(wsU + U_WHH) + (size_t)g * 256 * 2048;
  const char* whlB = (const char*)(wsU + U_WHL) + (size_t)g * 256 * 2048;
  const char* xbB = (const char*)xbp;

  const int arow = tid >> 2, akq = (tid & 3) * 8;
  const int abyte = swz_addr(arow, (tid & 3) * 16);
  int an0, akb;                    // decode for A cp16 staging (tid<256)
  dec_swz(tid * 16, an0, akb);
  float av[8];

  const f32x4 z4 = {0.f, 0.f, 0.f, 0.f};
  f32x4 acc[2][4];
#pragma unroll
  for (int i = 0; i < 2; ++i)
#pragma unroll
    for (int j = 0; j < 4; ++j) acc[i][j] = z4;

#define H_LOADA_DET(kt) \
  if (tid < 256) { \
    const float* p = deter + (size_t)(m0 + arow) * 2048 + g * 256 + (kt) * 32 + akq; \
    float4 u_ = ld4(p), w_ = ld4(p + 4); \
    av[0] = u_.x; av[1] = u_.y; av[2] = u_.z; av[3] = u_.w; \
    av[4] = w_.x; av[5] = w_.y; av[6] = w_.z; av[7] = w_.w; \
  }
#define H_WRITEA(buf) \
  if (tid < 256) { \
    s16x8 h8, l8; \
    _Pragma("unroll") \
    for (int j = 0; j < 8; ++j) { \
      ushort h_, l_; split2(av[j], h_, l_); \
      h8[j] = (short)h_; l8[j] = (short)l_; \
    } \
    *(s16x8*)((char*)Ah[buf] + abyte) = h8; \
    *(s16x8*)((char*)Al[buf] + abyte) = l8; \
  }
#define H_ISSUEA(buf, kt) \
  if (tid < 256) { \
    size_t rb = (size_t)(m0 + an0) * 3072; \
    int co = ((kt) * 32 - 256) * 2 + akb; \
    cp16g((char*)Ah[buf] + tid * 16, xbB + rb + co); \
    cp16g((char*)Al[buf] + tid * 16, xbB + rb + 1536 + co); \
  }
#define H_ISSUEW(buf, kt) { \
    size_t o0_ = (size_t)wn0 * 2048 + (kt) * 64 + wkb0; \
    size_t o1_ = (size_t)wn1 * 2048 + (kt) * 64 + wkb1; \
    cp16g((char*)Wh[buf] + tid * 16, whhB + o0_); \
    cp16g((char*)Wh[buf] + 8192 + tid * 16, whhB + o1_); \
    cp16g((char*)Wl[buf] + tid * 16, whlB + o0_); \
    cp16g((char*)Wl[buf] + 8192 + tid * 16, whlB + o1_); \
  }

  H_LOADA_DET(0);
  H_ISSUEW(0, 0);
  H_WRITEA(0);
  __syncthreads();
  int cur = 0;
  for (int t = 0; t < 32; ++t) {
    const bool pf = (t + 1 < 32);
    const bool det = (t + 1 < 8);
    if (pf) {
      H_ISSUEW(cur ^ 1, t + 1);
      if (det) { H_LOADA_DET(t + 1); }
      else     { H_ISSUEA(cur ^ 1, t + 1); }
    }
    const int k16 = (lane >> 4) * 16;
    s16x8 afh[2], afl[2];
#pragma unroll
    for (int mf = 0; mf < 2; ++mf) {
      int by = swz_addr(wr * 32 + mf * 16 + (lane & 15), k16);
      afh[mf] = *(const s16x8*)((const char*)Ah[cur] + by);
      afl[mf] = *(const s16x8*)((const char*)Al[cur] + by);
    }
#pragma unroll
    for (int nf = 0; nf < 4; ++nf) {
      int by = swz_addr(wc * 64 + nf * 16 + (lane & 15), k16);
      s16x8 bh = *(const s16x8*)((const char*)Wh[cur] + by);
      s16x8 bl = *(const s16x8*)((const char*)Wl[cur] + by);
#pragma unroll
      for (int mf = 0; mf < 2; ++mf) {
        acc[mf][nf] = mfma16(afh[mf], bh, acc[mf][nf]);
        acc[mf][nf] = mfma16(afh[mf], bl, acc[mf][nf]);
        acc[mf][nf] = mfma16(afl[mf], bh, acc[mf][nf]);
      }
    }
    if (pf && det) { H_WRITEA(cur ^ 1); }
    __syncthreads();
    cur ^= 1;
  }
#undef H_LOADA_DET
#undef H_WRITEA
#undef H_ISSUEA
#undef H_ISSUEW
#pragma unroll
  for (int mf = 0; mf < 2; ++mf) {
    int rbase = m0 + wr * 32 + mf * 16 + ((lane >> 4) << 2);
#pragma unroll
    for (int nf = 0; nf < 4; ++nf) {
      int col = wc * 64 + nf * 16 + (lane & 15);
      float b = hbias[g * 256 + col];
#pragma unroll
      for (int r = 0; r < 4; ++r)
        yh[(size_t)(rbase + r) * 2048 + g * 256 + col] = acc[mf][nf][r] + b;
    }
  }
}

// ---------------- rmsnorm(2048)+silu -> in-place packed [2048h|2048l] bf16 ----------------
__global__ __launch_bounds__(256) void k_rmsnorm2048(
    float* __restrict__ xh, const float* __restrict__ scale) {
  const int b = blockIdx.x, tid = threadIdx.x;
  float* row = xh + (size_t)b * 2048;
  float4 v0 = ld4(row + tid * 8);
  float4 v1 = ld4(row + tid * 8 + 4);
  float ss = v0.x * v0.x + v0.y * v0.y + v0.z * v0.z + v0.w * v0.w +
             v1.x * v1.x + v1.y * v1.y + v1.z * v1.z + v1.w * v1.w;
#pragma unroll
  for (int off = 32; off; off >>= 1) ss += __shfl_xor(ss, off);
  __shared__ float wsum[4];
  if ((tid & 63) == 0) wsum[tid >> 6] = ss;
  __syncthreads();   // also orders all row-reads before the packed overwrite
  float tot = wsum[0] + wsum[1] + wsum[2] + wsum[3];
  float inv = 1.0f / sqrtf(tot * (1.0f / 2048.0f) + EPSN);
  float4 sc0 = ld4(scale + tid * 8);
  float4 sc1 = ld4(scale + tid * 8 + 4);
  float o[8];
  o[0] = siluf(v0.x * inv * sc0.x); o[1] = siluf(v0.y * inv * sc0.y);
  o[2] = siluf(v0.z * inv * sc0.z); o[3] = siluf(v0.w * inv * sc0.w);
  o[4] = siluf(v1.x * inv * sc1.x); o[5] = siluf(v1.y * inv * sc1.y);
  o[6] = siluf(v1.z * inv * sc1.z); o[7] = siluf(v1.w * inv * sc1.w);
  s16x8 h8, l8;
#pragma unroll
  for (int j = 0; j < 8; ++j) {
    ushort h, l; split2(o[j], h, l);
    h8[j] = (short)h; l8[j] = (short)l;
  }
  ushort* rp = (ushort*)row;
  *(s16x8*)(rp + tid * 8) = h8;
  *(s16x8*)(rp + 2048 + tid * 8) = l8;
}

// ---------------- gru: A via cp16 from packed xh planes; single barrier/tile ----------------
__global__ __launch_bounds__(512) void k_grum(
    const ushort* __restrict__ xhp, const ushort* __restrict__ wsU,
    const float* __restrict__ gb, const float* __restrict__ deter,
    float* __restrict__ newdet) {
  __shared__ ushort Ah[2][128 * 32], Al[2][128 * 32];
  __shared__ ushort Wh[2][192 * 32], Wl[2][192 * 32];
  const int tid = threadIdx.x, lane = tid & 63, wv = tid >> 6;
  const int wr = wv >> 2, wc = wv & 3;
  const int g = blockIdx.x & 7;
  const int nc = (int)(blockIdx.x >> 3) & 3;
  const int m0 = (int)(blockIdx.x >> 5) * 128;

  int wn0, wkb0, wn1, wkb1;
  dec_swz(tid * 16, wn0, wkb0);
  dec_swz(8192 + tid * 16, wn1, wkb1);
  const char* wghB = (const char*)(wsU + U_WGH);
  const char* wglB = (const char*)(wsU + U_WGL);
  const size_t wo0 = (size_t)(g * 768 + ((wn0 >> 6) << 8) + nc * 64 + (wn0 & 63)) * 512 + wkb0;
  const size_t wo1 = (size_t)(g * 768 + ((wn1 >> 6) << 8) + nc * 64 + (wn1 & 63)) * 512 + wkb1;

  const char* xhB = (const char*)xhp;
  int an0, akb;
  dec_swz(tid * 16, an0, akb);   // A tile 128 rows x 64B; all 512 threads stage

  const f32x4 z4 = {0.f, 0.f, 0.f, 0.f};
  f32x4 acc[4][3];
#pragma unroll
  for (int i = 0; i < 4; ++i)
#pragma unroll
    for (int j = 0; j < 3; ++j) acc[i][j] = z4;

#define G_ISSUEA(buf, kt) { \
    size_t rb = (size_t)(m0 + an0) * 8192; \
    int co = (g * 256 + (kt) * 32) * 2 + akb; \
    cp16g((char*)Ah[buf] + tid * 16, xhB + rb + co); \
    cp16g((char*)Al[buf] + tid * 16, xhB + rb + 4096 + co); \
  }
#define G_ISSUEW(buf, kt) { \
    cp16g((char*)Wh[buf] + tid * 16, wghB + wo0 + (kt) * 64); \
    cp16g((char*)Wl[buf] + tid * 16, wglB + wo0 + (kt) * 64); \
    if (tid < 256) { \
      cp16g((char*)Wh[buf] + 8192 + tid * 16, wghB + wo1 + (kt) * 64); \
      cp16g((char*)Wl[buf] + 8192 + tid * 16, wglB + wo1 + (kt) * 64); \
    } }

  G_ISSUEW(0, 0);
  G_ISSUEA(0, 0);
  __syncthreads();
  int cur = 0;
  for (int t = 0; t < 8; ++t) {
    if (t + 1 < 8) { G_ISSUEW(cur ^ 1, t + 1); G_ISSUEA(cur ^ 1, t + 1); }
    const int k16 = (lane >> 4) * 16;
    s16x8 afh[4], afl[4];
#pragma unroll
    for (int mf = 0; mf < 4; ++mf) {
      int by = swz_addr(wr * 64 + mf * 16 + (lane & 15), k16);
      afh[mf] = *(const s16x8*)((const char*)Ah[cur] + by);
      afl[mf] = *(const s16x8*)((const char*)Al[cur] + by);
    }
#pragma unroll
    for (int gt = 0; gt < 3; ++gt) {
      int by = swz_addr(gt * 64 + wc * 16 + (lane & 15), k16);
      s16x8 bh = *(const s16x8*)((const char*)Wh[cur] + by);
      s16x8 bl = *(const s16x8*)((const char*)Wl[cur] + by);
#pragma unroll
      for (int mf = 0; mf < 4; ++mf) {
        acc[mf][gt] = mfma16(afh[mf], bh, acc[mf][gt]);
        acc[mf][gt] = mfma16(afh[mf], bl, acc[mf][gt]);
        acc[mf][gt] = mfma16(afl[mf], bh, acc[mf][gt]);
      }
    }
    __syncthreads();
    cur ^= 1;
  }
#undef G_ISSUEA
#undef G_ISSUEW
  const int col = nc * 64 + wc * 16 + (lane & 15);
  const float br = gb[g * 768 + col];
  const float bc = gb[g * 768 + 256 + col];
  const float bu = gb[g * 768 + 512 + col];
#pragma unroll
  for (int mf = 0; mf < 4; ++mf) {
    int rbase = m0 + wr * 64 + mf * 16 + ((lane >> 4) << 2);
#pragma unroll
    for (int r = 0; r < 4; ++r) {
      int row = rbase + r;
      float rr = sigm(acc[mf][0][r] + br);
      float cc = acc[mf][1][r] + bc;
      float uu = sigm(acc[mf][2][r] + bu - 1.0f);
      float d = deter[(size_t)row * 2048 + g * 256 + col];
      newdet[(size_t)row * 2048 + g * 256 + col] =
          uu * tanhf(rr * cc) + (1.0f - uu) * d;
    }
  }
}

// ---------------- obs_out: A via cp16 from packed hb; single barrier/tile ----------------
__global__ __launch_bounds__(512) void k_obsoutm(
    const ushort* __restrict__ hbp, const ushort* __restrict__ wsU,
    const float* __restrict__ ob, float* __restrict__ logit) {
  __shared__ ushort Ah[2][64 * 32], Al[2][64 * 32];
  __shared__ ushort Wh[2][256 * 32], Wl[2][256 * 32];
  const int tid = threadIdx.x, lane = tid & 63, wv = tid >> 6;
  const int wr = wv >> 2, wc = wv & 3;
  const int half = blockIdx.x & 1;
  const int m0 = (int)(blockIdx.x >> 1) * 64;

  int wn0, wkb0, wn1, wkb1;
  dec_swz(tid * 16, wn0, wkb0);
  dec_swz(8192 + tid * 16, wn1, wkb1);
  const char* whB = (const char*)(wsU + U_WOH) + (size_t)half * 256 * 512;
  const char* wlB = (const char*)(wsU + U_WOL) + (size_t)half * 256 * 512;
  const size_t wo0 = (size_t)wn0 * 512 + wkb0;
  const size_t wo1 = (size_t)wn1 * 512 + wkb1;

  const char* hbB = (const char*)hbp;
  int an0, akb;
  dec_swz(tid * 16, an0, akb);

  const f32x4 z4 = {0.f, 0.f, 0.f, 0.f};
  f32x4 acc[2][4];
#pragma unroll
  for (int i = 0; i < 2; ++i)
#pragma unroll
    for (int j = 0; j < 4; ++j) acc[i][j] = z4;

#define O_ISSUEA(buf, kt) \
  if (tid < 256) { \
    size_t rb = (size_t)(m0 + an0) * 1024; \
    int co = (kt) * 64 + akb; \
    cp16g((char*)Ah[buf] + tid * 16, hbB + rb + co); \
    cp16g((char*)Al[buf] + tid * 16, hbB + rb + 512 + co); \
  }
#define O_ISSUEW(buf, kt) { \
    cp16g((char*)Wh[buf] + tid * 16, whB + wo0 + (kt) * 64); \
    cp16g((char*)Wh[buf] + 8192 + tid * 16, whB + wo1 + (kt) * 64); \
    cp16g((char*)Wl[buf] + tid * 16, wlB + wo0 + (kt) * 64); \
    cp16g((char*)Wl[buf] + 8192 + tid * 16, wlB + wo1 + (kt) * 64); \
  }

  O_ISSUEW(0, 0);
  O_ISSUEA(0, 0);
  __syncthreads();
  int cur = 0;
  for (int t = 0; t < 8; ++t) {
    if (t + 1 < 8) { O_ISSUEW(cur ^ 1, t + 1); O_ISSUEA(cur ^ 1, t + 1); }
    const int k16 = (lane >> 4) * 16;
    s16x8 afh[2], afl[2];
#pragma unroll
    for (int mf = 0; mf < 2; ++mf) {
      int by = swz_addr(wr * 32 + mf * 16 + (lane & 15), k16);
      afh[mf] = *(const s16x8*)((const char*)Ah[cur] + by);
      afl[mf] = *(const s16x8*)((const char*)Al[cur] + by);
    }
#pragma unroll
    for (int nf = 0; nf < 4; ++nf) {
      int by = swz_addr(wc * 64 + nf * 16 + (lane & 15), k16);
      s16x8 bh = *(const s16x8*)((const char*)Wh[cur] + by);
      s16x8 bl = *(const s16x8*)((const char*)Wl[cur] + by);
#pragma unroll
      for (int mf = 0; mf < 2; ++mf) {
        acc[mf][nf] = mfma16(afh[mf], bh, acc[mf][nf]);
        acc[mf][nf] = mfma16(afh[mf], bl, acc[mf][nf]);
        acc[mf][nf] = mfma16(afl[mf], bh, acc[mf][nf]);
      }
    }
    __syncthreads();
    cur ^= 1;
  }
#undef O_ISSUEA
#undef O_ISSUEW
#pragma unroll
  for (int mf = 0; mf < 2; ++mf) {
    int rbase = m0 + wr * 32 + mf * 16 + ((lane >> 4) << 2);
#pragma unroll
    for (int nf = 0; nf < 4; ++nf) {
      int col = half * 256 + wc * 64 + nf * 16 + (lane & 15);
      float b = ob[col];
#pragma unroll
      for (int r = 0; r < 4; ++r)
        logit[(size_t)(rbase + r) * 512 + col] = acc[mf][nf][r] + b;
    }
  }
}

// ---------------- argmax -> one-hot (first-index ties) ----------------
__global__ __launch_bounds__(256) void k_argmax(
    const float* __restrict__ logit, float* __restrict__ stoch_out) {
  const size_t row = blockIdx.x * 4 + (threadIdx.x >> 6);
  const int lane = threadIdx.x & 63;
  const float* lp = logit + row * 512 + lane * 8;
  float4 a = ld4(lp), b = ld4(lp + 4);
  float v[8] = {a.x, a.y, a.z, a.w, b.x, b.y, b.z, b.w};
  float bv = v[0]; int bi = 0;
#pragma unroll
  for (int j = 1; j < 8; ++j)
    if (v[j] > bv) { bv = v[j]; bi = j; }
  bi += lane * 8;
  float pv = __shfl_xor(bv, 1);
  int   pi = __shfl_xor(bi, 1);
  if (pv > bv || (pv == bv && pi < bi)) { bv = pv; bi = pi; }
  float4 o0, o1;
  int base = lane * 8;
  o0.x = (bi == base + 0) ? 1.f : 0.f;
  o0.y = (bi == base + 1) ? 1.f : 0.f;
  o0.z = (bi == base + 2) ? 1.f : 0.f;
  o0.w = (bi == base + 3) ? 1.f : 0.f;
  o1.x = (bi == base + 4) ? 1.f : 0.f;
  o1.y = (bi == base + 5) ? 1.f : 0.f;
  o1.z = (bi == base + 6) ? 1.f : 0.f;
  o1.w = (bi == base + 7) ? 1.f : 0.f;
  st4(stoch_out + row * 512 + base, o0);
  st4(stoch_out + row * 512 + base + 4, o1);
}

// ---------------- launcher ----------------
extern "C" void kernel_launch(void* const* d_in, const int* in_sizes, int n_in,
                              void* d_out, int out_size, void* d_ws, size_t ws_size,
                              hipStream_t stream) {
  (void)in_sizes; (void)n_in; (void)out_size; (void)ws_size;
  const float* stoch      = (const float*)d_in[0];
  const float* deter      = (const float*)d_in[1];
  const float* action     = (const float*)d_in[2];
  const float* embed      = (const float*)d_in[3];
  const float* in0_w      = (const float*)d_in[4];
  const float* in0_b      = (const float*)d_in[5];
  const float* n0_s       = (const float*)d_in[6];
  const float* in1_w      = (const float*)d_in[7];
  const float* in1_b      = (const float*)d_in[8];
  const float* n1_s       = (const float*)d_in[9];
  const float* in2_w      = (const float*)d_in[10];
  const float* in2_b      = (const float*)d_in[11];
  const float* n2_s       = (const float*)d_in[12];
  const float* hid0_k     = (const float*)d_in[13];
  const float* hid0_b     = (const float*)d_in[14];
  const float* hidn_s     = (const float*)d_in[15];
  const float* gru_k      = (const float*)d_in[16];
  const float* gru_b      = (const float*)d_in[17];
  const float* obs_fc0_w  = (const float*)d_in[18];
  const float* obs_fc0_b  = (const float*)d_in[19];
  const float* obs_n_s    = (const float*)d_in[20];
  const float* obs_out_w  = (const float*)d_in[21];
  const float* obs_out_b  = (const float*)d_in[22];

  float*  out = (float*)d_out;
  float*  ws  = (float*)d_ws;
  ushort* wsU = (ushort*)d_ws;
  ushort* xbp = (ushort*)(ws + F_XB);
  float*  xh  = ws + F_XH;               // f32 yh, then packed planes in place
  ushort* xhp = (ushort*)(ws + F_XH);
  ushort* hbp = (ushort*)(ws + F_HB);    // inside xh, after mode-1 partials
  float*  part = xh;

  hipLaunchKernelGGL(k_prep, dim3(2176), dim3(256), 0, stream,
                     hid0_k, gru_k, in0_w, in1_w, obs_fc0_w, obs_out_w, wsU);
  hipLaunchKernelGGL(k_x2, dim3(32), dim3(512), 0, stream,
                     action, in2_w, in2_b, n2_s, xbp);
  hipLaunchKernelGGL(k_gemm256, dim3(384), dim3(512), 0, stream,
                     0, deter, stoch, out + OFF_DETER, embed, wsU, part);
  hipLaunchKernelGGL(k_comb_in, dim3(2048), dim3(256), 0, stream,
                     part, in0_b, n0_s, in1_b, n1_s, xbp);
  hipLaunchKernelGGL(k_hid0m, dim3(512), dim3(512), 0, stream,
                     deter, xbp, wsU, hid0_b, xh);
  hipLaunchKernelGGL(k_rmsnorm2048, dim3(4096), dim3(256), 0, stream, xh, hidn_s);
  hipLaunchKernelGGL(k_grum, dim3(1024), dim3(512), 0, stream,
                     xhp, wsU, gru_b, deter, out + OFF_DETER);
  hipLaunchKernelGGL(k_gemm256, dim3(256), dim3(512), 0, stream,
                     1, deter, stoch, out + OFF_DETER, embed, wsU, part);
  hipLaunchKernelGGL(k_comb4, dim3(1024), dim3(256), 0, stream,
                     part, obs_fc0_b, obs_n_s, hbp);
  hipLaunchKernelGGL(k_obsoutm, dim3(128), dim3(512), 0, stream,
                     hbp, wsU, obs_out_b, out + OFF_LOGIT);
  hipLaunchKernelGGL(k_argmax, dim3(1024), dim3(256), 0, stream,
                     out + OFF_LOGIT, out + OFF_STOCH);
}